// Round 12
// baseline (238.170 us; speedup 1.0000x reference)
//
#include <hip/hip_runtime.h>

// ============================================================================
// ShiftedWindowAttention — bf16 MFMA pipeline, v12.
// B=16,H=W=64,C=256,NH=8,HD=32, win 8x8 (N=64), shift 4 -> 1024 windows.
//
// stats_f32 -> finalize(q) -> rpbm -> wf_prep(4 weights) ->
// gemm_fullk (k+v_s+v_sh; full-K LDS panel, 1 barrier, 8 waves) ->
// finalize(k) -> attn_mega.
//
// Round-12 changes (v11 gemm: VGPR=68 -> staging loads serialized; stride
// 264/72 u16 = 4 mod 32 words -> 8-way LDS conflicts, 3.9M cycles):
//  * gemm staging: batched va[16] load phase then cvt+write (16 loads in
//    flight / thread)
//  * conflict-free strides: A_s 268, Xl 268, P 76 (both = 6 mod 32 words)
// ============================================================================

typedef unsigned short u16;
typedef unsigned int u32;
typedef __attribute__((ext_vector_type(8))) short bf16x8;   // 8 bf16 = 4 VGPR
typedef __attribute__((ext_vector_type(4))) float f32x4;

__device__ __forceinline__ float b2f(u16 u) {
  return __uint_as_float(((u32)u) << 16);
}
// native conversion -> v_cvt_pk_bf16_f32 (RNE)
__device__ __forceinline__ u16 f2b(float f) {
  return __builtin_bit_cast(u16, (__bf16)f);
}
__device__ __forceinline__ u32 pk2(float a, float b) {
  return (u32)f2b(a) | ((u32)f2b(b) << 16);
}
__device__ __forceinline__ bf16x8 pk8(float4 v0, float4 v1) {
  uint4 w;
  w.x = pk2(v0.x, v0.y); w.y = pk2(v0.z, v0.w);
  w.z = pk2(v1.x, v1.y); w.w = pk2(v1.z, v1.w);
  return __builtin_bit_cast(bf16x8, w);
}

// ---------------------------------------------------------------------------
// q stats, atomic-free partials.
// ---------------------------------------------------------------------------
__global__ __launch_bounds__(256) void stats_f32(const float* __restrict__ src,
                                                 float* __restrict__ ps,
                                                 float* __restrict__ pq) {
  const int blk = blockIdx.x;          // 1024 = b(16) * chunk(64)
  const int b = blk >> 6;
  const int p0 = (blk & 63) << 6;
  const int c = threadIdx.x;
  const float* p = src + (((size_t)(b << 12) + p0) << 8) + c;
  float s = 0.f, sq = 0.f;
#pragma unroll 8
  for (int i = 0; i < 64; ++i) {
    float v = p[(size_t)i << 8];
    s += v;
    sq = fmaf(v, v, sq);
  }
  ps[(blk << 8) + c] = s;
  pq[(blk << 8) + c] = sq;
}

__global__ void finalize_stats(const float* __restrict__ ps,
                               const float* __restrict__ pq,
                               float* __restrict__ A, float* __restrict__ Bo,
                               float scale) {
  const int i = blockIdx.x * 256 + threadIdx.x;  // 4096
  const int b = i >> 8, c = i & 255;
  const float* s0 = ps + ((size_t)(b << 6) << 8) + c;
  const float* q0 = pq + ((size_t)(b << 6) << 8) + c;
  float s = 0.f, sq = 0.f;
#pragma unroll 8
  for (int j = 0; j < 64; ++j) {
    s += s0[(size_t)j << 8];
    sq += q0[(size_t)j << 8];
  }
  float m = s * (1.f / 4096.f);
  float v = sq * (1.f / 4096.f) - m * m;
  float a = rsqrtf(v + 1e-5f) * scale;
  A[i] = a;
  Bo[i] = -m * a;
}

// ---------------------------------------------------------------------------
// rpb + mask fused, MFMA D-fragment order.
// ---------------------------------------------------------------------------
__global__ __launch_bounds__(256) void rpbm_prep(const float* __restrict__ rpb,
                                                 float* __restrict__ rpbm) {
  const int idx = blockIdx.x * 256 + threadIdx.x;  // 131072
  const int t = idx & 63;
  const int lane = (idx >> 6) & 63;
  const int h = (idx >> 12) & 7;
  const int var = idx >> 15;
  const int cf = t >> 4, rf = (t >> 2) & 3, r = t & 3;
  const int n = ((lane >> 4) << 2) + r + (rf << 4);
  const int m = (lane & 15) + (cf << 4);
  const int vh = var >> 1, vw = var & 1;
  const int ln = (vh ? (1 + ((n >> 3) >= 4)) : 0) * 3 + (vw ? (1 + ((n & 7) >= 4)) : 0);
  const int lm = (vh ? (1 + ((m >> 3) >= 4)) : 0) * 3 + (vw ? (1 + ((m & 7) >= 4)) : 0);
  rpbm[idx] = rpb[(h << 12) + (n << 6) + m] + ((ln == lm) ? 0.f : -100.f);
}

// ---------------------------------------------------------------------------
// All weights -> bf16 fragment order wf[w][cf][ks][g][u][8]:
// oc = cf*16+u, ic = ks*32+g*8+j.  w: 0=kW 1=vWs 2=vWh 3=pW.
// Per-weight block = 8192 fragments x 8 u16 = 65536 u16.
// ---------------------------------------------------------------------------
__global__ __launch_bounds__(256) void wf_prep(const float* __restrict__ w0,
                                               const float* __restrict__ w1,
                                               const float* __restrict__ w2,
                                               const float* __restrict__ w3,
                                               u16* __restrict__ wf) {
  const int idx = blockIdx.x * 256 + threadIdx.x;  // 8192 per weight
  const int u_ = idx & 15, g_ = (idx >> 4) & 3, ks_ = (idx >> 6) & 7,
            cf_ = idx >> 9;
  const int oc = (cf_ << 4) + u_, ic = (ks_ << 5) + (g_ << 3);
  const float* srcs[4] = {w0, w1, w2, w3};
  const float* p = srcs[blockIdx.y] + (size_t)oc * 256 + ic;
  float4 v0 = *(const float4*)p;
  float4 v1 = *(const float4*)(p + 4);
  *(bf16x8*)(wf + (size_t)blockIdx.y * 65536 + (size_t)idx * 8) = pk8(v0, v1);
}

// ---------------------------------------------------------------------------
// Full-K stage-once GEMM, 8 thin waves:
// dst = gather_window_shift(src) @ W^T + bias, bf16 out, fragment order.
// Block = 512 thr = 8 waves (2 row x 4 col), BM=128, BN=256, K=256 staged
// once (A_s[128][268] bf16, 68.6KB -> 2 blocks/CU = 16 waves/CU). ONE
// barrier. W-fragments direct from L2-resident wf. grid (512, 3).
// Stride 268 u16 = 134 words = 6 mod 32 -> conflict-free b128 reads.
// ---------------------------------------------------------------------------
__global__ __launch_bounds__(512) void gemm_fullk(
    const float* __restrict__ ksrc, const float* __restrict__ vs,
    const float* __restrict__ vsh, const u16* __restrict__ wf,
    const float* __restrict__ kbias, const float* __restrict__ vbs,
    const float* __restrict__ vbh, u16* __restrict__ klin,
    u16* __restrict__ vt, float* __restrict__ kps, float* __restrict__ kpq) {
  const int mode = blockIdx.y;
  const float* src;
  const float* bias;
  u16* dst;
  if (mode == 0)      { src = ksrc; bias = kbias; dst = klin; }
  else if (mode == 1) { src = vs;   bias = vbs;  dst = vt; }
  else                { src = vsh;  bias = vbh;  dst = vt + 16777216; }
  const u16* wfm = wf + (size_t)mode * 65536;

  __shared__ u16 A_s[128][268];
  const int t = threadIdx.x;
  const int bx = blockIdx.x;

  // ---- stage A panel: batched loads (16 in flight), then cvt+write ----
  {
    const int row = t >> 2;
    const int c0 = (t & 3) << 6;
    const int rg = (bx << 7) + row;
    const int bb = rg >> 12, rr = rg & 4095, wi = rr >> 6, nn = rr & 63;
    const int hs = ((wi >> 3) << 3) + (nn >> 3);
    const int wsq = ((wi & 7) << 3) + (nn & 7);
    const float* ap = src +
        ((((size_t)((bb << 6) | ((hs + 4) & 63)) << 6) | ((wsq + 4) & 63)) << 8) + c0;
    float4 va[16];
#pragma unroll
    for (int q = 0; q < 16; ++q) va[q] = *(const float4*)(ap + (q << 2));
#pragma unroll
    for (int q = 0; q < 8; ++q)
      *(bf16x8*)&A_s[row][c0 + (q << 3)] = pk8(va[2 * q], va[2 * q + 1]);
  }
  __syncthreads();  // the only barrier

  const int wid = t >> 6, l = t & 63, u = l & 15, g = l >> 4;
  const int wr = wid >> 2, wc = wid & 3;
  const int win = (bx << 1) | wr;

  f32x4 acc[4][4];
#pragma unroll
  for (int i = 0; i < 4; ++i)
#pragma unroll
    for (int j = 0; j < 4; ++j) acc[i][j] = {0.f, 0.f, 0.f, 0.f};

#pragma unroll
  for (int ks = 0; ks < 8; ++ks) {
    bf16x8 bfr[4];
#pragma unroll
    for (int cf = 0; cf < 4; ++cf)
      bfr[cf] = *(const bf16x8*)(wfm +
          ((((size_t)(((wc << 2) | cf) << 3) | ks) << 2 | g) << 4 | u) * 8);
    bf16x8 a[4];
#pragma unroll
    for (int rf = 0; rf < 4; ++rf)
      a[rf] = *(const bf16x8*)&A_s[(wr << 6) + (rf << 4) + u][(ks << 5) + (g << 3)];
#pragma unroll
    for (int rf = 0; rf < 4; ++rf)
#pragma unroll
      for (int cf = 0; cf < 4; ++cf)
        acc[rf][cf] = __builtin_amdgcn_mfma_f32_16x16x32_bf16(a[rf], bfr[cf],
                                                              acc[rf][cf], 0, 0, 0);
  }

  // ---- epilogue: fragment-order stores (+ fused k-stats for mode 0) ----
#pragma unroll
  for (int cf = 0; cf < 4; ++cf) {
    const int col = (wc << 6) + (cf << 4) + u;
    const float bv = bias[col];
    float s = 0.f, sq = 0.f;
#pragma unroll
    for (int rf = 0; rf < 4; ++rf) {
      if (mode == 0) {
        // klin: [win][h][cf_tok][g][u][8j]; token = (rf<<4)+(g<<2)+r, ch=col
        const int hh = col >> 5;
        const int ga = (col >> 3) & 3;
        const int j = col & 7;
        const size_t base =
            ((size_t)((win << 3) | hh) << 11) + (rf << 9) + (ga << 7) + j;
#pragma unroll
        for (int r = 0; r < 4; ++r) {
          u16 hv = f2b(acc[rf][cf][r] + bv);
          dst[base + (((g << 2) + r) << 3)] = hv;
          float rv = b2f(hv);
          s += rv;
          sq = fmaf(rv, rv, sq);
        }
      } else {
        // vt: [win][h][df][ks][g][u][8j]; d-ch = col, token = (rf<<4)+(g<<2)+r
        const int hh = col >> 5;
        const int df = (col >> 4) & 1;
        const int ks_ = rf >> 1;
        const int ga = ((rf & 1) << 1) | (g >> 1);
        const size_t base = ((size_t)((win << 3) | hh) << 11) + (df << 10) +
                            (ks_ << 9) + (ga << 7) + (u << 3) + ((g & 1) << 2);
        u32 w0 = pk2(acc[rf][cf][0] + bv, acc[rf][cf][1] + bv);
        u32 w1 = pk2(acc[rf][cf][2] + bv, acc[rf][cf][3] + bv);
        *(uint2*)(dst + base) = make_uint2(w0, w1);
      }
    }
    if (mode == 0) {
      s += __shfl_xor(s, 16);
      s += __shfl_xor(s, 32);
      sq += __shfl_xor(sq, 16);
      sq += __shfl_xor(sq, 32);
      if (g == 0) {
        kps[(win << 8) + col] = s;
        kpq[(win << 8) + col] = sq;
      }
    }
  }
}

// ---------------------------------------------------------------------------
// Fused attention + projection. Block = window (1024), 512 thr = 8 waves,
// wave = head. QK^T -> softmax -> P (wave-private LDS) -> pf regs ->
// barrier -> per-branch {vf load, PV, Xl[br] write} -> barrier ->
// per-branch {proj, reverse-shift f32 scatter}. 2 barriers.
// Strides P=76, Xl=268 (both 6 mod 32 words -> conflict-free b128 reads);
// union 77.8KB -> still 2 blocks/CU.
// ---------------------------------------------------------------------------
union AttnSh {
  u16 P[8][64][76];     // 77824 B
  u16 Xl[2][64][268];   // 68608 B
};

__global__ __launch_bounds__(512) void attn_mega(
    const float* __restrict__ qsrc, const float* __restrict__ qA_,
    const float* __restrict__ qB_, const u16* __restrict__ klin,
    const float* __restrict__ kA_, const float* __restrict__ kB_,
    const u16* __restrict__ vt, const float* __restrict__ rpbm,
    const u16* __restrict__ pwf, const float* __restrict__ pbias,
    float* __restrict__ outp) {
  __shared__ AttnSh sh;
  const int tid = threadIdx.x;
  const int wid = tid >> 6;      // head
  const int l = tid & 63;
  const int u = l & 15;
  const int g = l >> 4;
  const int win = blockIdx.x;
  const int h = wid;
  const int b = win >> 6;
  const int wIdx = win & 63;
  const int wh = wIdx >> 3, ww = wIdx & 7;
  const int var = ((wh == 7) ? 2 : 0) | ((ww == 7) ? 1 : 0);
  const int coff = (h << 5) + (g << 3);

  float qav[8], qbv[8], kav[8], kbv[8];
  {
    const int o = (b << 8) + coff;
    float4 a0 = *(const float4*)(qA_ + o), a1 = *(const float4*)(qA_ + o + 4);
    float4 b0 = *(const float4*)(qB_ + o), b1 = *(const float4*)(qB_ + o + 4);
    float4 c0v = *(const float4*)(kA_ + o), c1 = *(const float4*)(kA_ + o + 4);
    float4 d0v = *(const float4*)(kB_ + o), d1 = *(const float4*)(kB_ + o + 4);
    qav[0]=a0.x;qav[1]=a0.y;qav[2]=a0.z;qav[3]=a0.w;qav[4]=a1.x;qav[5]=a1.y;qav[6]=a1.z;qav[7]=a1.w;
    qbv[0]=b0.x;qbv[1]=b0.y;qbv[2]=b0.z;qbv[3]=b0.w;qbv[4]=b1.x;qbv[5]=b1.y;qbv[6]=b1.z;qbv[7]=b1.w;
    kav[0]=c0v.x;kav[1]=c0v.y;kav[2]=c0v.z;kav[3]=c0v.w;kav[4]=c1.x;kav[5]=c1.y;kav[6]=c1.z;kav[7]=c1.w;
    kbv[0]=d0v.x;kbv[1]=d0v.y;kbv[2]=d0v.z;kbv[3]=d0v.w;kbv[4]=d1.x;kbv[5]=d1.y;kbv[6]=d1.z;kbv[7]=d1.w;
  }

  // q fragments (gathered + normalized + scaled)
  bf16x8 qf[4];
#pragma unroll
  for (int rf = 0; rf < 4; ++rf) {
    const int n = (rf << 4) + u;
    const int nhs = (wh << 3) + (n >> 3);
    const int nws = (ww << 3) + (n & 7);
    const float* qp = qsrc +
        ((((size_t)((b << 6) | ((nhs + 4) & 63)) << 6) | ((nws + 4) & 63)) << 8) + coff;
    float4 v0 = *(const float4*)qp;
    float4 v1 = *(const float4*)(qp + 4);
    float qv[8] = {v0.x, v0.y, v0.z, v0.w, v1.x, v1.y, v1.z, v1.w};
#pragma unroll
    for (int j = 0; j < 8; ++j) qf[rf][j] = (short)f2b(fmaf(qv[j], qav[j], qbv[j]));
  }

  // k fragments — fragment-ordered klin: wave read = 64 lanes x 16B contiguous
  const u16* kp = klin + ((size_t)((win << 3) | h) << 11);
  bf16x8 kf[4];
#pragma unroll
  for (int cf = 0; cf < 4; ++cf) {
    union { uint4 v; u16 s[8]; } raw;
    raw.v = *(const uint4*)(kp + (cf << 9) + (g << 7) + (u << 3));
#pragma unroll
    for (int j = 0; j < 8; ++j)
      kf[cf][j] = (short)f2b(fmaf(b2f(raw.s[j]), kav[j], kbv[j]));
  }

  // S = q k^T
  f32x4 s[4][4];
  const f32x4 z4 = {0.f, 0.f, 0.f, 0.f};
#pragma unroll
  for (int rf = 0; rf < 4; ++rf)
#pragma unroll
    for (int cf = 0; cf < 4; ++cf)
      s[rf][cf] = __builtin_amdgcn_mfma_f32_16x16x32_bf16(qf[rf], kf[cf], z4, 0, 0, 0);

  // + rpb + mask (pre-fused, fragment order)
  const float* rb = rpbm + ((((var << 3) + h) << 6) + l) * 64;
#pragma unroll
  for (int cf = 0; cf < 4; ++cf)
#pragma unroll
    for (int rf = 0; rf < 4; ++rf) {
      float4 bv = *(const float4*)(rb + (cf << 4) + (rf << 2));
      s[rf][cf][0] += bv.x; s[rf][cf][1] += bv.y;
      s[rf][cf][2] += bv.z; s[rf][cf][3] += bv.w;
    }

  // softmax over m (4 col-frags x 16 lanes)
#pragma unroll
  for (int rf = 0; rf < 4; ++rf) {
#pragma unroll
    for (int r = 0; r < 4; ++r) {
      float m0 = fmaxf(fmaxf(s[rf][0][r], s[rf][1][r]),
                       fmaxf(s[rf][2][r], s[rf][3][r]));
      m0 = fmaxf(m0, __shfl_xor(m0, 1));
      m0 = fmaxf(m0, __shfl_xor(m0, 2));
      m0 = fmaxf(m0, __shfl_xor(m0, 4));
      m0 = fmaxf(m0, __shfl_xor(m0, 8));
      float t0 = 0.f;
#pragma unroll
      for (int cf = 0; cf < 4; ++cf) {
        s[rf][cf][r] = __expf(s[rf][cf][r] - m0);
        t0 += s[rf][cf][r];
      }
      t0 += __shfl_xor(t0, 1);
      t0 += __shfl_xor(t0, 2);
      t0 += __shfl_xor(t0, 4);
      t0 += __shfl_xor(t0, 8);
      const float inv = 1.f / t0;
#pragma unroll
      for (int cf = 0; cf < 4; ++cf) s[rf][cf][r] *= inv;
    }
  }

  // P -> LDS (wave-private; own-wave readback needs no barrier)
#pragma unroll
  for (int rf = 0; rf < 4; ++rf)
#pragma unroll
    for (int r = 0; r < 4; ++r) {
      const int n = (rf << 4) + (g << 2) + r;
#pragma unroll
      for (int cf = 0; cf < 4; ++cf)
        sh.P[wid][n][(cf << 4) + u] = f2b(s[rf][cf][r]);
    }

  // pf fragments into regs (lane-transpose), once for both branches
  bf16x8 pf[4][2];
#pragma unroll
  for (int cf = 0; cf < 4; ++cf)
#pragma unroll
    for (int ks = 0; ks < 2; ++ks)
      pf[cf][ks] = *(const bf16x8*)&sh.P[wid][(cf << 4) + u][(ks << 5) + (g << 3)];

  __syncthreads();  // barrier #1: all waves hold pf -> P space reusable as Xl

  // PV per branch (xt reused -> lower register liveness)
  const u16* vbase = vt + ((size_t)((win << 3) | h) << 11);
#pragma unroll
  for (int br = 0; br < 2; ++br) {
    bf16x8 vf[2][2];
#pragma unroll
    for (int df = 0; df < 2; ++df)
#pragma unroll
      for (int ks = 0; ks < 2; ++ks)
        vf[df][ks] = *(const bf16x8*)(vbase + (size_t)br * 16777216 +
                                      (df << 10) + (ks << 9) + (g << 7) + (u << 3));
    f32x4 xt[2][4];
#pragma unroll
    for (int df = 0; df < 2; ++df)
#pragma unroll
      for (int cf = 0; cf < 4; ++cf) xt[df][cf] = z4;
#pragma unroll
    for (int cf = 0; cf < 4; ++cf)
#pragma unroll
      for (int ks = 0; ks < 2; ++ks) {
        xt[0][cf] = __builtin_amdgcn_mfma_f32_16x16x32_bf16(
            vf[0][ks], pf[cf][ks], xt[0][cf], 0, 0, 0);
        xt[1][cf] = __builtin_amdgcn_mfma_f32_16x16x32_bf16(
            vf[1][ks], pf[cf][ks], xt[1][cf], 0, 0, 0);
      }
    // X -> LDS: tok = cf*16+u, ch = h*32 + df*16 + g*4
#pragma unroll
    for (int df = 0; df < 2; ++df)
#pragma unroll
      for (int cf = 0; cf < 4; ++cf) {
        const int tok = (cf << 4) + u;
        const int ch = (h << 5) + (df << 4) + (g << 2);
        *(u32*)&sh.Xl[br][tok][ch] = pk2(xt[df][cf][0], xt[df][cf][1]);
        *(u32*)&sh.Xl[br][tok][ch + 2] = pk2(xt[df][cf][2], xt[df][cf][3]);
      }
  }
  __syncthreads();  // barrier #2: Xl complete

  // cooperative proj per branch; wave owns oc in [32*wid, 32*wid+32)
#pragma unroll
  for (int br = 0; br < 2; ++br) {
    f32x4 acc[4][2];
#pragma unroll
    for (int mf = 0; mf < 4; ++mf)
#pragma unroll
      for (int cfi = 0; cfi < 2; ++cfi) acc[mf][cfi] = z4;
#pragma unroll
    for (int ks = 0; ks < 8; ++ks) {
      bf16x8 a[4];
#pragma unroll
      for (int mf = 0; mf < 4; ++mf)
        a[mf] = *(const bf16x8*)&sh.Xl[br][(mf << 4) + u][(ks << 5) + (g << 3)];
      bf16x8 bw[2];
#pragma unroll
      for (int cfi = 0; cfi < 2; ++cfi) {
        const int cf = (wid << 1) | cfi;
        bw[cfi] = *(const bf16x8*)(pwf +
            ((((((size_t)(cf << 3) | ks) << 2) | g) << 4 | u) << 3));
      }
#pragma unroll
      for (int mf = 0; mf < 4; ++mf)
#pragma unroll
        for (int cfi = 0; cfi < 2; ++cfi)
          acc[mf][cfi] = __builtin_amdgcn_mfma_f32_16x16x32_bf16(
              a[mf], bw[cfi], acc[mf][cfi], 0, 0, 0);
    }

    // epilogue: +bias, reverse-shift scatter
    float* ob = outp + (size_t)br * 16777216;
#pragma unroll
    for (int cfi = 0; cfi < 2; ++cfi) {
      const int oc = (((wid << 1) | cfi) << 4) + u;
      const float bv = pbias[oc];
#pragma unroll
      for (int mf = 0; mf < 4; ++mf) {
#pragma unroll
        for (int r = 0; r < 4; ++r) {
          const int tok = (mf << 4) + (g << 2) + r;
          const int nhs = (wh << 3) + (tok >> 3);
          const int nws = (ww << 3) + (tok & 7);
          ob[((((size_t)((b << 6) | ((nhs + 4) & 63)) << 6) |
               ((nws + 4) & 63)) << 8) + oc] = acc[mf][cfi][r] + bv;
        }
      }
    }
  }
}

// ---------------------------------------------------------------------------
extern "C" void kernel_launch(void* const* d_in, const int* in_sizes, int n_in,
                              void* d_out, int out_size, void* d_ws,
                              size_t ws_size, hipStream_t stream) {
  (void)in_sizes; (void)n_in; (void)out_size; (void)ws_size;
  const float* q   = (const float*)d_in[0];
  const float* k   = (const float*)d_in[1];
  const float* vs  = (const float*)d_in[2];
  const float* vsh = (const float*)d_in[3];
  const float* kW  = (const float*)d_in[4];
  const float* kb  = (const float*)d_in[5];
  const float* vWs = (const float*)d_in[6];
  const float* vbs = (const float*)d_in[7];
  const float* vWh = (const float*)d_in[8];
  const float* vbh = (const float*)d_in[9];
  const float* pW  = (const float*)d_in[10];
  const float* pb  = (const float*)d_in[11];
  const float* rpb = (const float*)d_in[12];
  float* out = (float*)d_out;

  float* f = (float*)d_ws;
  float* qps = f;                       // 262144
  float* qpq = f + 262144;              // 262144
  float* kps = f + 524288;              // 262144
  float* kpq = f + 786432;              // 262144
  float* qA  = f + 1048576;
  float* qB  = f + 1052672;
  float* kA  = f + 1056768;
  float* kB  = f + 1060864;
  float* rpbm = f + 1064960;            // 131072 floats
  u16* wfall = (u16*)(f + 1196032);     // 4 x 65536 u16 = 131072 floats
  u16* klin  = (u16*)(f + 1327104);     // 16.77M u16 = 8388608 floats
  u16* vt    = (u16*)(f + 9715712);     // 33.55M u16 (2 branches)
  u16* pwf   = wfall + 3 * 65536;

  stats_f32<<<1024, 256, 0, stream>>>(q, qps, qpq);
  finalize_stats<<<16, 256, 0, stream>>>(qps, qpq, qA, qB,
                                         0.17677669529663687f);  // 1/sqrt(32)
  rpbm_prep<<<512, 256, 0, stream>>>(rpb, rpbm);
  wf_prep<<<dim3(32, 4), 256, 0, stream>>>(kW, vWs, vWh, pW, wfall);

  gemm_fullk<<<dim3(512, 3), 512, 0, stream>>>(k, vs, vsh, wfall,
                                               kb, vbs, vbh,
                                               klin, vt, kps, kpq);
  finalize_stats<<<16, 256, 0, stream>>>(kps, kpq, kA, kB, 1.0f);

  attn_mega<<<1024, 512, 0, stream>>>(q, qA, qB, klin, kA, kB, vt, rpbm,
                                      pwf, pb, out);
}

// Round 13
// 209.533 us; speedup vs baseline: 1.1367x; 1.1367x over previous
//
#include <hip/hip_runtime.h>

// ============================================================================
// ShiftedWindowAttention — bf16 MFMA pipeline, v13.
// B=16,H=W=64,C=256,NH=8,HD=32, win 8x8 (N=64), shift 4 -> 1024 windows.
//
// stats_f32 -> finalize(q) -> rpbm -> wf_prep(4 weights) ->
// gemm_fullk (k+v_s+v_sh; full-K LDS panel, 1 barrier, 8 waves) ->
// finalize(k) -> attn_mega.
//
// Round-13: v12's +4-pad strides (268/76 u16) broke 16B alignment of
// ds_read_b128 (split to b64 pairs, attn +39us). v11's 264/72 strides are
// 16B-aligned with only benign 2-way aliasing (m136: free). REVERT strides
// to 264/72; KEEP v12's batched va[16] staging in gemm (that part helped).
// ============================================================================

typedef unsigned short u16;
typedef unsigned int u32;
typedef __attribute__((ext_vector_type(8))) short bf16x8;   // 8 bf16 = 4 VGPR
typedef __attribute__((ext_vector_type(4))) float f32x4;

__device__ __forceinline__ float b2f(u16 u) {
  return __uint_as_float(((u32)u) << 16);
}
// native conversion -> v_cvt_pk_bf16_f32 (RNE)
__device__ __forceinline__ u16 f2b(float f) {
  return __builtin_bit_cast(u16, (__bf16)f);
}
__device__ __forceinline__ u32 pk2(float a, float b) {
  return (u32)f2b(a) | ((u32)f2b(b) << 16);
}
__device__ __forceinline__ bf16x8 pk8(float4 v0, float4 v1) {
  uint4 w;
  w.x = pk2(v0.x, v0.y); w.y = pk2(v0.z, v0.w);
  w.z = pk2(v1.x, v1.y); w.w = pk2(v1.z, v1.w);
  return __builtin_bit_cast(bf16x8, w);
}

// ---------------------------------------------------------------------------
// q stats, atomic-free partials.
// ---------------------------------------------------------------------------
__global__ __launch_bounds__(256) void stats_f32(const float* __restrict__ src,
                                                 float* __restrict__ ps,
                                                 float* __restrict__ pq) {
  const int blk = blockIdx.x;          // 1024 = b(16) * chunk(64)
  const int b = blk >> 6;
  const int p0 = (blk & 63) << 6;
  const int c = threadIdx.x;
  const float* p = src + (((size_t)(b << 12) + p0) << 8) + c;
  float s = 0.f, sq = 0.f;
#pragma unroll 8
  for (int i = 0; i < 64; ++i) {
    float v = p[(size_t)i << 8];
    s += v;
    sq = fmaf(v, v, sq);
  }
  ps[(blk << 8) + c] = s;
  pq[(blk << 8) + c] = sq;
}

__global__ void finalize_stats(const float* __restrict__ ps,
                               const float* __restrict__ pq,
                               float* __restrict__ A, float* __restrict__ Bo,
                               float scale) {
  const int i = blockIdx.x * 256 + threadIdx.x;  // 4096
  const int b = i >> 8, c = i & 255;
  const float* s0 = ps + ((size_t)(b << 6) << 8) + c;
  const float* q0 = pq + ((size_t)(b << 6) << 8) + c;
  float s = 0.f, sq = 0.f;
#pragma unroll 8
  for (int j = 0; j < 64; ++j) {
    s += s0[(size_t)j << 8];
    sq += q0[(size_t)j << 8];
  }
  float m = s * (1.f / 4096.f);
  float v = sq * (1.f / 4096.f) - m * m;
  float a = rsqrtf(v + 1e-5f) * scale;
  A[i] = a;
  Bo[i] = -m * a;
}

// ---------------------------------------------------------------------------
// rpb + mask fused, MFMA D-fragment order.
// ---------------------------------------------------------------------------
__global__ __launch_bounds__(256) void rpbm_prep(const float* __restrict__ rpb,
                                                 float* __restrict__ rpbm) {
  const int idx = blockIdx.x * 256 + threadIdx.x;  // 131072
  const int t = idx & 63;
  const int lane = (idx >> 6) & 63;
  const int h = (idx >> 12) & 7;
  const int var = idx >> 15;
  const int cf = t >> 4, rf = (t >> 2) & 3, r = t & 3;
  const int n = ((lane >> 4) << 2) + r + (rf << 4);
  const int m = (lane & 15) + (cf << 4);
  const int vh = var >> 1, vw = var & 1;
  const int ln = (vh ? (1 + ((n >> 3) >= 4)) : 0) * 3 + (vw ? (1 + ((n & 7) >= 4)) : 0);
  const int lm = (vh ? (1 + ((m >> 3) >= 4)) : 0) * 3 + (vw ? (1 + ((m & 7) >= 4)) : 0);
  rpbm[idx] = rpb[(h << 12) + (n << 6) + m] + ((ln == lm) ? 0.f : -100.f);
}

// ---------------------------------------------------------------------------
// All weights -> bf16 fragment order wf[w][cf][ks][g][u][8]:
// oc = cf*16+u, ic = ks*32+g*8+j.  w: 0=kW 1=vWs 2=vWh 3=pW.
// Per-weight block = 8192 fragments x 8 u16 = 65536 u16.
// ---------------------------------------------------------------------------
__global__ __launch_bounds__(256) void wf_prep(const float* __restrict__ w0,
                                               const float* __restrict__ w1,
                                               const float* __restrict__ w2,
                                               const float* __restrict__ w3,
                                               u16* __restrict__ wf) {
  const int idx = blockIdx.x * 256 + threadIdx.x;  // 8192 per weight
  const int u_ = idx & 15, g_ = (idx >> 4) & 3, ks_ = (idx >> 6) & 7,
            cf_ = idx >> 9;
  const int oc = (cf_ << 4) + u_, ic = (ks_ << 5) + (g_ << 3);
  const float* srcs[4] = {w0, w1, w2, w3};
  const float* p = srcs[blockIdx.y] + (size_t)oc * 256 + ic;
  float4 v0 = *(const float4*)p;
  float4 v1 = *(const float4*)(p + 4);
  *(bf16x8*)(wf + (size_t)blockIdx.y * 65536 + (size_t)idx * 8) = pk8(v0, v1);
}

// ---------------------------------------------------------------------------
// Full-K stage-once GEMM, 8 thin waves:
// dst = gather_window_shift(src) @ W^T + bias, bf16 out, fragment order.
// Block = 512 thr = 8 waves (2 row x 4 col), BM=128, BN=256, K=256 staged
// once (A_s[128][264] bf16, 67.6KB -> 2 blocks/CU = 16 waves/CU). ONE
// barrier. W-fragments direct from L2-resident wf. grid (512, 3).
// Stride 264 u16 = 528B: 16B-aligned b128, 2-way aliasing only (free).
// ---------------------------------------------------------------------------
__global__ __launch_bounds__(512) void gemm_fullk(
    const float* __restrict__ ksrc, const float* __restrict__ vs,
    const float* __restrict__ vsh, const u16* __restrict__ wf,
    const float* __restrict__ kbias, const float* __restrict__ vbs,
    const float* __restrict__ vbh, u16* __restrict__ klin,
    u16* __restrict__ vt, float* __restrict__ kps, float* __restrict__ kpq) {
  const int mode = blockIdx.y;
  const float* src;
  const float* bias;
  u16* dst;
  if (mode == 0)      { src = ksrc; bias = kbias; dst = klin; }
  else if (mode == 1) { src = vs;   bias = vbs;  dst = vt; }
  else                { src = vsh;  bias = vbh;  dst = vt + 16777216; }
  const u16* wfm = wf + (size_t)mode * 65536;

  __shared__ u16 A_s[128][264];
  const int t = threadIdx.x;
  const int bx = blockIdx.x;

  // ---- stage A panel: batched loads (16 in flight), then cvt+write ----
  {
    const int row = t >> 2;
    const int c0 = (t & 3) << 6;
    const int rg = (bx << 7) + row;
    const int bb = rg >> 12, rr = rg & 4095, wi = rr >> 6, nn = rr & 63;
    const int hs = ((wi >> 3) << 3) + (nn >> 3);
    const int wsq = ((wi & 7) << 3) + (nn & 7);
    const float* ap = src +
        ((((size_t)((bb << 6) | ((hs + 4) & 63)) << 6) | ((wsq + 4) & 63)) << 8) + c0;
    float4 va[16];
#pragma unroll
    for (int q = 0; q < 16; ++q) va[q] = *(const float4*)(ap + (q << 2));
#pragma unroll
    for (int q = 0; q < 8; ++q)
      *(bf16x8*)&A_s[row][c0 + (q << 3)] = pk8(va[2 * q], va[2 * q + 1]);
  }
  __syncthreads();  // the only barrier

  const int wid = t >> 6, l = t & 63, u = l & 15, g = l >> 4;
  const int wr = wid >> 2, wc = wid & 3;
  const int win = (bx << 1) | wr;

  f32x4 acc[4][4];
#pragma unroll
  for (int i = 0; i < 4; ++i)
#pragma unroll
    for (int j = 0; j < 4; ++j) acc[i][j] = {0.f, 0.f, 0.f, 0.f};

#pragma unroll
  for (int ks = 0; ks < 8; ++ks) {
    bf16x8 bfr[4];
#pragma unroll
    for (int cf = 0; cf < 4; ++cf)
      bfr[cf] = *(const bf16x8*)(wfm +
          ((((size_t)(((wc << 2) | cf) << 3) | ks) << 2 | g) << 4 | u) * 8);
    bf16x8 a[4];
#pragma unroll
    for (int rf = 0; rf < 4; ++rf)
      a[rf] = *(const bf16x8*)&A_s[(wr << 6) + (rf << 4) + u][(ks << 5) + (g << 3)];
#pragma unroll
    for (int rf = 0; rf < 4; ++rf)
#pragma unroll
      for (int cf = 0; cf < 4; ++cf)
        acc[rf][cf] = __builtin_amdgcn_mfma_f32_16x16x32_bf16(a[rf], bfr[cf],
                                                              acc[rf][cf], 0, 0, 0);
  }

  // ---- epilogue: fragment-order stores (+ fused k-stats for mode 0) ----
#pragma unroll
  for (int cf = 0; cf < 4; ++cf) {
    const int col = (wc << 6) + (cf << 4) + u;
    const float bv = bias[col];
    float s = 0.f, sq = 0.f;
#pragma unroll
    for (int rf = 0; rf < 4; ++rf) {
      if (mode == 0) {
        // klin: [win][h][cf_tok][g][u][8j]; token = (rf<<4)+(g<<2)+r, ch=col
        const int hh = col >> 5;
        const int ga = (col >> 3) & 3;
        const int j = col & 7;
        const size_t base =
            ((size_t)((win << 3) | hh) << 11) + (rf << 9) + (ga << 7) + j;
#pragma unroll
        for (int r = 0; r < 4; ++r) {
          u16 hv = f2b(acc[rf][cf][r] + bv);
          dst[base + (((g << 2) + r) << 3)] = hv;
          float rv = b2f(hv);
          s += rv;
          sq = fmaf(rv, rv, sq);
        }
      } else {
        // vt: [win][h][df][ks][g][u][8j]; d-ch = col, token = (rf<<4)+(g<<2)+r
        const int hh = col >> 5;
        const int df = (col >> 4) & 1;
        const int ks_ = rf >> 1;
        const int ga = ((rf & 1) << 1) | (g >> 1);
        const size_t base = ((size_t)((win << 3) | hh) << 11) + (df << 10) +
                            (ks_ << 9) + (ga << 7) + (u << 3) + ((g & 1) << 2);
        u32 w0 = pk2(acc[rf][cf][0] + bv, acc[rf][cf][1] + bv);
        u32 w1 = pk2(acc[rf][cf][2] + bv, acc[rf][cf][3] + bv);
        *(uint2*)(dst + base) = make_uint2(w0, w1);
      }
    }
    if (mode == 0) {
      s += __shfl_xor(s, 16);
      s += __shfl_xor(s, 32);
      sq += __shfl_xor(sq, 16);
      sq += __shfl_xor(sq, 32);
      if (g == 0) {
        kps[(win << 8) + col] = s;
        kpq[(win << 8) + col] = sq;
      }
    }
  }
}

// ---------------------------------------------------------------------------
// Fused attention + projection (v11 layout restored). Block = window (1024),
// 512 thr = 8 waves, wave = head. QK^T -> softmax -> P (wave-private LDS) ->
// pf regs -> barrier -> per-branch {vf load, PV, Xl[br] write} -> barrier ->
// per-branch {proj, reverse-shift f32 scatter}. 2 barriers.
// Strides P=72, Xl=264: 16B-aligned b128, benign 2-way aliasing.
// ---------------------------------------------------------------------------
union AttnSh {
  u16 P[8][64][72];     // 73728 B
  u16 Xl[2][64][264];   // 67584 B
};

__global__ __launch_bounds__(512) void attn_mega(
    const float* __restrict__ qsrc, const float* __restrict__ qA_,
    const float* __restrict__ qB_, const u16* __restrict__ klin,
    const float* __restrict__ kA_, const float* __restrict__ kB_,
    const u16* __restrict__ vt, const float* __restrict__ rpbm,
    const u16* __restrict__ pwf, const float* __restrict__ pbias,
    float* __restrict__ outp) {
  __shared__ AttnSh sh;
  const int tid = threadIdx.x;
  const int wid = tid >> 6;      // head
  const int l = tid & 63;
  const int u = l & 15;
  const int g = l >> 4;
  const int win = blockIdx.x;
  const int h = wid;
  const int b = win >> 6;
  const int wIdx = win & 63;
  const int wh = wIdx >> 3, ww = wIdx & 7;
  const int var = ((wh == 7) ? 2 : 0) | ((ww == 7) ? 1 : 0);
  const int coff = (h << 5) + (g << 3);

  float qav[8], qbv[8], kav[8], kbv[8];
  {
    const int o = (b << 8) + coff;
    float4 a0 = *(const float4*)(qA_ + o), a1 = *(const float4*)(qA_ + o + 4);
    float4 b0 = *(const float4*)(qB_ + o), b1 = *(const float4*)(qB_ + o + 4);
    float4 c0v = *(const float4*)(kA_ + o), c1 = *(const float4*)(kA_ + o + 4);
    float4 d0v = *(const float4*)(kB_ + o), d1 = *(const float4*)(kB_ + o + 4);
    qav[0]=a0.x;qav[1]=a0.y;qav[2]=a0.z;qav[3]=a0.w;qav[4]=a1.x;qav[5]=a1.y;qav[6]=a1.z;qav[7]=a1.w;
    qbv[0]=b0.x;qbv[1]=b0.y;qbv[2]=b0.z;qbv[3]=b0.w;qbv[4]=b1.x;qbv[5]=b1.y;qbv[6]=b1.z;qbv[7]=b1.w;
    kav[0]=c0v.x;kav[1]=c0v.y;kav[2]=c0v.z;kav[3]=c0v.w;kav[4]=c1.x;kav[5]=c1.y;kav[6]=c1.z;kav[7]=c1.w;
    kbv[0]=d0v.x;kbv[1]=d0v.y;kbv[2]=d0v.z;kbv[3]=d0v.w;kbv[4]=d1.x;kbv[5]=d1.y;kbv[6]=d1.z;kbv[7]=d1.w;
  }

  // q fragments (gathered + normalized + scaled)
  bf16x8 qf[4];
#pragma unroll
  for (int rf = 0; rf < 4; ++rf) {
    const int n = (rf << 4) + u;
    const int nhs = (wh << 3) + (n >> 3);
    const int nws = (ww << 3) + (n & 7);
    const float* qp = qsrc +
        ((((size_t)((b << 6) | ((nhs + 4) & 63)) << 6) | ((nws + 4) & 63)) << 8) + coff;
    float4 v0 = *(const float4*)qp;
    float4 v1 = *(const float4*)(qp + 4);
    float qv[8] = {v0.x, v0.y, v0.z, v0.w, v1.x, v1.y, v1.z, v1.w};
#pragma unroll
    for (int j = 0; j < 8; ++j) qf[rf][j] = (short)f2b(fmaf(qv[j], qav[j], qbv[j]));
  }

  // k fragments — fragment-ordered klin: wave read = 64 lanes x 16B contiguous
  const u16* kp = klin + ((size_t)((win << 3) | h) << 11);
  bf16x8 kf[4];
#pragma unroll
  for (int cf = 0; cf < 4; ++cf) {
    union { uint4 v; u16 s[8]; } raw;
    raw.v = *(const uint4*)(kp + (cf << 9) + (g << 7) + (u << 3));
#pragma unroll
    for (int j = 0; j < 8; ++j)
      kf[cf][j] = (short)f2b(fmaf(b2f(raw.s[j]), kav[j], kbv[j]));
  }

  // S = q k^T
  f32x4 s[4][4];
  const f32x4 z4 = {0.f, 0.f, 0.f, 0.f};
#pragma unroll
  for (int rf = 0; rf < 4; ++rf)
#pragma unroll
    for (int cf = 0; cf < 4; ++cf)
      s[rf][cf] = __builtin_amdgcn_mfma_f32_16x16x32_bf16(qf[rf], kf[cf], z4, 0, 0, 0);

  // + rpb + mask (pre-fused, fragment order)
  const float* rb = rpbm + ((((var << 3) + h) << 6) + l) * 64;
#pragma unroll
  for (int cf = 0; cf < 4; ++cf)
#pragma unroll
    for (int rf = 0; rf < 4; ++rf) {
      float4 bv = *(const float4*)(rb + (cf << 4) + (rf << 2));
      s[rf][cf][0] += bv.x; s[rf][cf][1] += bv.y;
      s[rf][cf][2] += bv.z; s[rf][cf][3] += bv.w;
    }

  // softmax over m (4 col-frags x 16 lanes)
#pragma unroll
  for (int rf = 0; rf < 4; ++rf) {
#pragma unroll
    for (int r = 0; r < 4; ++r) {
      float m0 = fmaxf(fmaxf(s[rf][0][r], s[rf][1][r]),
                       fmaxf(s[rf][2][r], s[rf][3][r]));
      m0 = fmaxf(m0, __shfl_xor(m0, 1));
      m0 = fmaxf(m0, __shfl_xor(m0, 2));
      m0 = fmaxf(m0, __shfl_xor(m0, 4));
      m0 = fmaxf(m0, __shfl_xor(m0, 8));
      float t0 = 0.f;
#pragma unroll
      for (int cf = 0; cf < 4; ++cf) {
        s[rf][cf][r] = __expf(s[rf][cf][r] - m0);
        t0 += s[rf][cf][r];
      }
      t0 += __shfl_xor(t0, 1);
      t0 += __shfl_xor(t0, 2);
      t0 += __shfl_xor(t0, 4);
      t0 += __shfl_xor(t0, 8);
      const float inv = 1.f / t0;
#pragma unroll
      for (int cf = 0; cf < 4; ++cf) s[rf][cf][r] *= inv;
    }
  }

  // P -> LDS (wave-private; own-wave readback needs no barrier)
#pragma unroll
  for (int rf = 0; rf < 4; ++rf)
#pragma unroll
    for (int r = 0; r < 4; ++r) {
      const int n = (rf << 4) + (g << 2) + r;
#pragma unroll
      for (int cf = 0; cf < 4; ++cf)
        sh.P[wid][n][(cf << 4) + u] = f2b(s[rf][cf][r]);
    }

  // pf fragments into regs (lane-transpose), once for both branches
  bf16x8 pf[4][2];
#pragma unroll
  for (int cf = 0; cf < 4; ++cf)
#pragma unroll
    for (int ks = 0; ks < 2; ++ks)
      pf[cf][ks] = *(const bf16x8*)&sh.P[wid][(cf << 4) + u][(ks << 5) + (g << 3)];

  __syncthreads();  // barrier #1: all waves hold pf -> P space reusable as Xl

  // PV per branch (xt reused -> lower register liveness)
  const u16* vbase = vt + ((size_t)((win << 3) | h) << 11);
#pragma unroll
  for (int br = 0; br < 2; ++br) {
    bf16x8 vf[2][2];
#pragma unroll
    for (int df = 0; df < 2; ++df)
#pragma unroll
      for (int ks = 0; ks < 2; ++ks)
        vf[df][ks] = *(const bf16x8*)(vbase + (size_t)br * 16777216 +
                                      (df << 10) + (ks << 9) + (g << 7) + (u << 3));
    f32x4 xt[2][4];
#pragma unroll
    for (int df = 0; df < 2; ++df)
#pragma unroll
      for (int cf = 0; cf < 4; ++cf) xt[df][cf] = z4;
#pragma unroll
    for (int cf = 0; cf < 4; ++cf)
#pragma unroll
      for (int ks = 0; ks < 2; ++ks) {
        xt[0][cf] = __builtin_amdgcn_mfma_f32_16x16x32_bf16(
            vf[0][ks], pf[cf][ks], xt[0][cf], 0, 0, 0);
        xt[1][cf] = __builtin_amdgcn_mfma_f32_16x16x32_bf16(
            vf[1][ks], pf[cf][ks], xt[1][cf], 0, 0, 0);
      }
    // X -> LDS: tok = cf*16+u, ch = h*32 + df*16 + g*4
#pragma unroll
    for (int df = 0; df < 2; ++df)
#pragma unroll
      for (int cf = 0; cf < 4; ++cf) {
        const int tok = (cf << 4) + u;
        const int ch = (h << 5) + (df << 4) + (g << 2);
        *(u32*)&sh.Xl[br][tok][ch] = pk2(xt[df][cf][0], xt[df][cf][1]);
        *(u32*)&sh.Xl[br][tok][ch + 2] = pk2(xt[df][cf][2], xt[df][cf][3]);
      }
  }
  __syncthreads();  // barrier #2: Xl complete

  // cooperative proj per branch; wave owns oc in [32*wid, 32*wid+32)
#pragma unroll
  for (int br = 0; br < 2; ++br) {
    f32x4 acc[4][2];
#pragma unroll
    for (int mf = 0; mf < 4; ++mf)
#pragma unroll
      for (int cfi = 0; cfi < 2; ++cfi) acc[mf][cfi] = z4;
#pragma unroll
    for (int ks = 0; ks < 8; ++ks) {
      bf16x8 a[4];
#pragma unroll
      for (int mf = 0; mf < 4; ++mf)
        a[mf] = *(const bf16x8*)&sh.Xl[br][(mf << 4) + u][(ks << 5) + (g << 3)];
      bf16x8 bw[2];
#pragma unroll
      for (int cfi = 0; cfi < 2; ++cfi) {
        const int cf = (wid << 1) | cfi;
        bw[cfi] = *(const bf16x8*)(pwf +
            ((((((size_t)(cf << 3) | ks) << 2) | g) << 4 | u) << 3));
      }
#pragma unroll
      for (int mf = 0; mf < 4; ++mf)
#pragma unroll
        for (int cfi = 0; cfi < 2; ++cfi)
          acc[mf][cfi] = __builtin_amdgcn_mfma_f32_16x16x32_bf16(
              a[mf], bw[cfi], acc[mf][cfi], 0, 0, 0);
    }

    // epilogue: +bias, reverse-shift scatter
    float* ob = outp + (size_t)br * 16777216;
#pragma unroll
    for (int cfi = 0; cfi < 2; ++cfi) {
      const int oc = (((wid << 1) | cfi) << 4) + u;
      const float bv = pbias[oc];
#pragma unroll
      for (int mf = 0; mf < 4; ++mf) {
#pragma unroll
        for (int r = 0; r < 4; ++r) {
          const int tok = (mf << 4) + (g << 2) + r;
          const int nhs = (wh << 3) + (tok >> 3);
          const int nws = (ww << 3) + (tok & 7);
          ob[((((size_t)((b << 6) | ((nhs + 4) & 63)) << 6) |
               ((nws + 4) & 63)) << 8) + oc] = acc[mf][cfi][r] + bv;
        }
      }
    }
  }
}

// ---------------------------------------------------------------------------
extern "C" void kernel_launch(void* const* d_in, const int* in_sizes, int n_in,
                              void* d_out, int out_size, void* d_ws,
                              size_t ws_size, hipStream_t stream) {
  (void)in_sizes; (void)n_in; (void)out_size; (void)ws_size;
  const float* q   = (const float*)d_in[0];
  const float* k   = (const float*)d_in[1];
  const float* vs  = (const float*)d_in[2];
  const float* vsh = (const float*)d_in[3];
  const float* kW  = (const float*)d_in[4];
  const float* kb  = (const float*)d_in[5];
  const float* vWs = (const float*)d_in[6];
  const float* vbs = (const float*)d_in[7];
  const float* vWh = (const float*)d_in[8];
  const float* vbh = (const float*)d_in[9];
  const float* pW  = (const float*)d_in[10];
  const float* pb  = (const float*)d_in[11];
  const float* rpb = (const float*)d_in[12];
  float* out = (float*)d_out;

  float* f = (float*)d_ws;
  float* qps = f;                       // 262144
  float* qpq = f + 262144;              // 262144
  float* kps = f + 524288;              // 262144
  float* kpq = f + 786432;              // 262144
  float* qA  = f + 1048576;
  float* qB  = f + 1052672;
  float* kA  = f + 1056768;
  float* kB  = f + 1060864;
  float* rpbm = f + 1064960;            // 131072 floats
  u16* wfall = (u16*)(f + 1196032);     // 4 x 65536 u16 = 131072 floats
  u16* klin  = (u16*)(f + 1327104);     // 16.77M u16 = 8388608 floats
  u16* vt    = (u16*)(f + 9715712);     // 33.55M u16 (2 branches)
  u16* pwf   = wfall + 3 * 65536;

  stats_f32<<<1024, 256, 0, stream>>>(q, qps, qpq);
  finalize_stats<<<16, 256, 0, stream>>>(qps, qpq, qA, qB,
                                         0.17677669529663687f);  // 1/sqrt(32)
  rpbm_prep<<<512, 256, 0, stream>>>(rpb, rpbm);
  wf_prep<<<dim3(32, 4), 256, 0, stream>>>(kW, vWs, vWh, pW, wfall);

  gemm_fullk<<<dim3(512, 3), 512, 0, stream>>>(k, vs, vsh, wfall,
                                               kb, vbs, vbh,
                                               klin, vt, kps, kpq);
  finalize_stats<<<16, 256, 0, stream>>>(kps, kpq, kA, kB, 1.0f);

  attn_mega<<<1024, 512, 0, stream>>>(q, qA, qB, klin, kA, kB, vt, rpbm,
                                      pwf, pb, out);
}

// Round 14
// 198.501 us; speedup vs baseline: 1.1998x; 1.0556x over previous
//
#include <hip/hip_runtime.h>

// ============================================================================
// ShiftedWindowAttention — bf16 MFMA pipeline, v14.
// B=16,H=W=64,C=256,NH=8,HD=32, win 8x8 (N=64), shift 4 -> 1024 windows.
//
// stats_f32 -> finalize(q) -> rpbm -> wf_prep(4 weights) ->
// gemm_fullk (k+v_s+v_sh; BM=64 full-K LDS panel, 1 barrier, 4 waves) ->
// finalize(k) -> attn_mega (v13/v11 layout).
//
// Round-14: gemm is stage-latency bound (compute 320cy/wave vs staging
// ~3600cy; only 2 blocks/CU to overlap). BM 128->64 (one window/block),
// 256 thr, A_s[64][264]=33.8KB -> 4 blocks/CU = 4 staging streams.
// ============================================================================

typedef unsigned short u16;
typedef unsigned int u32;
typedef __attribute__((ext_vector_type(8))) short bf16x8;   // 8 bf16 = 4 VGPR
typedef __attribute__((ext_vector_type(4))) float f32x4;

__device__ __forceinline__ float b2f(u16 u) {
  return __uint_as_float(((u32)u) << 16);
}
// native conversion -> v_cvt_pk_bf16_f32 (RNE)
__device__ __forceinline__ u16 f2b(float f) {
  return __builtin_bit_cast(u16, (__bf16)f);
}
__device__ __forceinline__ u32 pk2(float a, float b) {
  return (u32)f2b(a) | ((u32)f2b(b) << 16);
}
__device__ __forceinline__ bf16x8 pk8(float4 v0, float4 v1) {
  uint4 w;
  w.x = pk2(v0.x, v0.y); w.y = pk2(v0.z, v0.w);
  w.z = pk2(v1.x, v1.y); w.w = pk2(v1.z, v1.w);
  return __builtin_bit_cast(bf16x8, w);
}

// ---------------------------------------------------------------------------
// q stats, atomic-free partials.
// ---------------------------------------------------------------------------
__global__ __launch_bounds__(256) void stats_f32(const float* __restrict__ src,
                                                 float* __restrict__ ps,
                                                 float* __restrict__ pq) {
  const int blk = blockIdx.x;          // 1024 = b(16) * chunk(64)
  const int b = blk >> 6;
  const int p0 = (blk & 63) << 6;
  const int c = threadIdx.x;
  const float* p = src + (((size_t)(b << 12) + p0) << 8) + c;
  float s = 0.f, sq = 0.f;
#pragma unroll 8
  for (int i = 0; i < 64; ++i) {
    float v = p[(size_t)i << 8];
    s += v;
    sq = fmaf(v, v, sq);
  }
  ps[(blk << 8) + c] = s;
  pq[(blk << 8) + c] = sq;
}

__global__ void finalize_stats(const float* __restrict__ ps,
                               const float* __restrict__ pq,
                               float* __restrict__ A, float* __restrict__ Bo,
                               float scale) {
  const int i = blockIdx.x * 256 + threadIdx.x;  // 4096
  const int b = i >> 8, c = i & 255;
  const float* s0 = ps + ((size_t)(b << 6) << 8) + c;
  const float* q0 = pq + ((size_t)(b << 6) << 8) + c;
  float s = 0.f, sq = 0.f;
#pragma unroll 8
  for (int j = 0; j < 64; ++j) {
    s += s0[(size_t)j << 8];
    sq += q0[(size_t)j << 8];
  }
  float m = s * (1.f / 4096.f);
  float v = sq * (1.f / 4096.f) - m * m;
  float a = rsqrtf(v + 1e-5f) * scale;
  A[i] = a;
  Bo[i] = -m * a;
}

// ---------------------------------------------------------------------------
// rpb + mask fused, MFMA D-fragment order.
// ---------------------------------------------------------------------------
__global__ __launch_bounds__(256) void rpbm_prep(const float* __restrict__ rpb,
                                                 float* __restrict__ rpbm) {
  const int idx = blockIdx.x * 256 + threadIdx.x;  // 131072
  const int t = idx & 63;
  const int lane = (idx >> 6) & 63;
  const int h = (idx >> 12) & 7;
  const int var = idx >> 15;
  const int cf = t >> 4, rf = (t >> 2) & 3, r = t & 3;
  const int n = ((lane >> 4) << 2) + r + (rf << 4);
  const int m = (lane & 15) + (cf << 4);
  const int vh = var >> 1, vw = var & 1;
  const int ln = (vh ? (1 + ((n >> 3) >= 4)) : 0) * 3 + (vw ? (1 + ((n & 7) >= 4)) : 0);
  const int lm = (vh ? (1 + ((m >> 3) >= 4)) : 0) * 3 + (vw ? (1 + ((m & 7) >= 4)) : 0);
  rpbm[idx] = rpb[(h << 12) + (n << 6) + m] + ((ln == lm) ? 0.f : -100.f);
}

// ---------------------------------------------------------------------------
// All weights -> bf16 fragment order wf[w][cf][ks][g][u][8]:
// oc = cf*16+u, ic = ks*32+g*8+j.  w: 0=kW 1=vWs 2=vWh 3=pW.
// Per-weight block = 8192 fragments x 8 u16 = 65536 u16.
// ---------------------------------------------------------------------------
__global__ __launch_bounds__(256) void wf_prep(const float* __restrict__ w0,
                                               const float* __restrict__ w1,
                                               const float* __restrict__ w2,
                                               const float* __restrict__ w3,
                                               u16* __restrict__ wf) {
  const int idx = blockIdx.x * 256 + threadIdx.x;  // 8192 per weight
  const int u_ = idx & 15, g_ = (idx >> 4) & 3, ks_ = (idx >> 6) & 7,
            cf_ = idx >> 9;
  const int oc = (cf_ << 4) + u_, ic = (ks_ << 5) + (g_ << 3);
  const float* srcs[4] = {w0, w1, w2, w3};
  const float* p = srcs[blockIdx.y] + (size_t)oc * 256 + ic;
  float4 v0 = *(const float4*)p;
  float4 v1 = *(const float4*)(p + 4);
  *(bf16x8*)(wf + (size_t)blockIdx.y * 65536 + (size_t)idx * 8) = pk8(v0, v1);
}

// ---------------------------------------------------------------------------
// Full-K stage-once GEMM, BM=64 (one window per block):
// dst = gather_window_shift(src) @ W^T + bias, bf16 out, fragment order.
// Block = 256 thr = 4 waves (wave wc owns cols [64wc,64wc+64), all 64 rows),
// K=256 staged once (A_s[64][264] bf16, 33.8KB -> 4 blocks/CU = 16 waves/CU,
// 4 independent staging streams). ONE barrier. W-fragments direct from
// L2-resident wf. grid (1024, 3): y = mode (0:k 1:v_s 2:v_sh).
// ---------------------------------------------------------------------------
__global__ __launch_bounds__(256) void gemm_fullk(
    const float* __restrict__ ksrc, const float* __restrict__ vs,
    const float* __restrict__ vsh, const u16* __restrict__ wf,
    const float* __restrict__ kbias, const float* __restrict__ vbs,
    const float* __restrict__ vbh, u16* __restrict__ klin,
    u16* __restrict__ vt, float* __restrict__ kps, float* __restrict__ kpq) {
  const int mode = blockIdx.y;
  const float* src;
  const float* bias;
  u16* dst;
  if (mode == 0)      { src = ksrc; bias = kbias; dst = klin; }
  else if (mode == 1) { src = vs;   bias = vbs;  dst = vt; }
  else                { src = vsh;  bias = vbh;  dst = vt + 16777216; }
  const u16* wfm = wf + (size_t)mode * 65536;

  __shared__ u16 A_s[64][264];
  const int t = threadIdx.x;
  const int bx = blockIdx.x;   // = window
  const int win = bx;

  // ---- stage A panel: 4 thr/row, 64 f32 each ----
  {
    const int row = t >> 2;           // 0..63 (token in window)
    const int c0 = (t & 3) << 6;
    const int rg = (bx << 6) + row;
    const int bb = rg >> 12, rr = rg & 4095, wi = rr >> 6, nn = rr & 63;
    const int hs = ((wi >> 3) << 3) + (nn >> 3);
    const int wsq = ((wi & 7) << 3) + (nn & 7);
    const float* ap = src +
        ((((size_t)((bb << 6) | ((hs + 4) & 63)) << 6) | ((wsq + 4) & 63)) << 8) + c0;
    float4 va[16];
#pragma unroll
    for (int q = 0; q < 16; ++q) va[q] = *(const float4*)(ap + (q << 2));
#pragma unroll
    for (int q = 0; q < 8; ++q)
      *(bf16x8*)&A_s[row][c0 + (q << 3)] = pk8(va[2 * q], va[2 * q + 1]);
  }
  __syncthreads();  // the only barrier

  const int wc = t >> 6, l = t & 63, u = l & 15, g = l >> 4;

  f32x4 acc[4][4];
#pragma unroll
  for (int i = 0; i < 4; ++i)
#pragma unroll
    for (int j = 0; j < 4; ++j) acc[i][j] = {0.f, 0.f, 0.f, 0.f};

#pragma unroll
  for (int ks = 0; ks < 8; ++ks) {
    bf16x8 bfr[4];
#pragma unroll
    for (int cf = 0; cf < 4; ++cf)
      bfr[cf] = *(const bf16x8*)(wfm +
          ((((size_t)(((wc << 2) | cf) << 3) | ks) << 2 | g) << 4 | u) * 8);
    bf16x8 a[4];
#pragma unroll
    for (int rf = 0; rf < 4; ++rf)
      a[rf] = *(const bf16x8*)&A_s[(rf << 4) + u][(ks << 5) + (g << 3)];
#pragma unroll
    for (int rf = 0; rf < 4; ++rf)
#pragma unroll
      for (int cf = 0; cf < 4; ++cf)
        acc[rf][cf] = __builtin_amdgcn_mfma_f32_16x16x32_bf16(a[rf], bfr[cf],
                                                              acc[rf][cf], 0, 0, 0);
  }

  // ---- epilogue: fragment-order stores (+ fused k-stats for mode 0) ----
#pragma unroll
  for (int cf = 0; cf < 4; ++cf) {
    const int col = (wc << 6) + (cf << 4) + u;
    const float bv = bias[col];
    float s = 0.f, sq = 0.f;
#pragma unroll
    for (int rf = 0; rf < 4; ++rf) {
      if (mode == 0) {
        // klin: [win][h][cf_tok][g][u][8j]; token = (rf<<4)+(g<<2)+r, ch=col
        const int hh = col >> 5;
        const int ga = (col >> 3) & 3;
        const int j = col & 7;
        const size_t base =
            ((size_t)((win << 3) | hh) << 11) + (rf << 9) + (ga << 7) + j;
#pragma unroll
        for (int r = 0; r < 4; ++r) {
          u16 hv = f2b(acc[rf][cf][r] + bv);
          dst[base + (((g << 2) + r) << 3)] = hv;
          float rv = b2f(hv);
          s += rv;
          sq = fmaf(rv, rv, sq);
        }
      } else {
        // vt: [win][h][df][ks][g][u][8j]; d-ch = col, token = (rf<<4)+(g<<2)+r
        const int hh = col >> 5;
        const int df = (col >> 4) & 1;
        const int ks_ = rf >> 1;
        const int ga = ((rf & 1) << 1) | (g >> 1);
        const size_t base = ((size_t)((win << 3) | hh) << 11) + (df << 10) +
                            (ks_ << 9) + (ga << 7) + (u << 3) + ((g & 1) << 2);
        u32 w0 = pk2(acc[rf][cf][0] + bv, acc[rf][cf][1] + bv);
        u32 w1 = pk2(acc[rf][cf][2] + bv, acc[rf][cf][3] + bv);
        *(uint2*)(dst + base) = make_uint2(w0, w1);
      }
    }
    if (mode == 0) {
      s += __shfl_xor(s, 16);
      s += __shfl_xor(s, 32);
      sq += __shfl_xor(sq, 16);
      sq += __shfl_xor(sq, 32);
      if (g == 0) {
        kps[(win << 8) + col] = s;
        kpq[(win << 8) + col] = sq;
      }
    }
  }
}

// ---------------------------------------------------------------------------
// Fused attention + projection (unchanged from v13). Block = window (1024),
// 512 thr = 8 waves, wave = head. 2 barriers. Strides P=72, Xl=264.
// ---------------------------------------------------------------------------
union AttnSh {
  u16 P[8][64][72];     // 73728 B
  u16 Xl[2][64][264];   // 67584 B
};

__global__ __launch_bounds__(512) void attn_mega(
    const float* __restrict__ qsrc, const float* __restrict__ qA_,
    const float* __restrict__ qB_, const u16* __restrict__ klin,
    const float* __restrict__ kA_, const float* __restrict__ kB_,
    const u16* __restrict__ vt, const float* __restrict__ rpbm,
    const u16* __restrict__ pwf, const float* __restrict__ pbias,
    float* __restrict__ outp) {
  __shared__ AttnSh sh;
  const int tid = threadIdx.x;
  const int wid = tid >> 6;      // head
  const int l = tid & 63;
  const int u = l & 15;
  const int g = l >> 4;
  const int win = blockIdx.x;
  const int h = wid;
  const int b = win >> 6;
  const int wIdx = win & 63;
  const int wh = wIdx >> 3, ww = wIdx & 7;
  const int var = ((wh == 7) ? 2 : 0) | ((ww == 7) ? 1 : 0);
  const int coff = (h << 5) + (g << 3);

  float qav[8], qbv[8], kav[8], kbv[8];
  {
    const int o = (b << 8) + coff;
    float4 a0 = *(const float4*)(qA_ + o), a1 = *(const float4*)(qA_ + o + 4);
    float4 b0 = *(const float4*)(qB_ + o), b1 = *(const float4*)(qB_ + o + 4);
    float4 c0v = *(const float4*)(kA_ + o), c1 = *(const float4*)(kA_ + o + 4);
    float4 d0v = *(const float4*)(kB_ + o), d1 = *(const float4*)(kB_ + o + 4);
    qav[0]=a0.x;qav[1]=a0.y;qav[2]=a0.z;qav[3]=a0.w;qav[4]=a1.x;qav[5]=a1.y;qav[6]=a1.z;qav[7]=a1.w;
    qbv[0]=b0.x;qbv[1]=b0.y;qbv[2]=b0.z;qbv[3]=b0.w;qbv[4]=b1.x;qbv[5]=b1.y;qbv[6]=b1.z;qbv[7]=b1.w;
    kav[0]=c0v.x;kav[1]=c0v.y;kav[2]=c0v.z;kav[3]=c0v.w;kav[4]=c1.x;kav[5]=c1.y;kav[6]=c1.z;kav[7]=c1.w;
    kbv[0]=d0v.x;kbv[1]=d0v.y;kbv[2]=d0v.z;kbv[3]=d0v.w;kbv[4]=d1.x;kbv[5]=d1.y;kbv[6]=d1.z;kbv[7]=d1.w;
  }

  // q fragments (gathered + normalized + scaled)
  bf16x8 qf[4];
#pragma unroll
  for (int rf = 0; rf < 4; ++rf) {
    const int n = (rf << 4) + u;
    const int nhs = (wh << 3) + (n >> 3);
    const int nws = (ww << 3) + (n & 7);
    const float* qp = qsrc +
        ((((size_t)((b << 6) | ((nhs + 4) & 63)) << 6) | ((nws + 4) & 63)) << 8) + coff;
    float4 v0 = *(const float4*)qp;
    float4 v1 = *(const float4*)(qp + 4);
    float qv[8] = {v0.x, v0.y, v0.z, v0.w, v1.x, v1.y, v1.z, v1.w};
#pragma unroll
    for (int j = 0; j < 8; ++j) qf[rf][j] = (short)f2b(fmaf(qv[j], qav[j], qbv[j]));
  }

  // k fragments — fragment-ordered klin: wave read = 64 lanes x 16B contiguous
  const u16* kp = klin + ((size_t)((win << 3) | h) << 11);
  bf16x8 kf[4];
#pragma unroll
  for (int cf = 0; cf < 4; ++cf) {
    union { uint4 v; u16 s[8]; } raw;
    raw.v = *(const uint4*)(kp + (cf << 9) + (g << 7) + (u << 3));
#pragma unroll
    for (int j = 0; j < 8; ++j)
      kf[cf][j] = (short)f2b(fmaf(b2f(raw.s[j]), kav[j], kbv[j]));
  }

  // S = q k^T
  f32x4 s[4][4];
  const f32x4 z4 = {0.f, 0.f, 0.f, 0.f};
#pragma unroll
  for (int rf = 0; rf < 4; ++rf)
#pragma unroll
    for (int cf = 0; cf < 4; ++cf)
      s[rf][cf] = __builtin_amdgcn_mfma_f32_16x16x32_bf16(qf[rf], kf[cf], z4, 0, 0, 0);

  // + rpb + mask (pre-fused, fragment order)
  const float* rb = rpbm + ((((var << 3) + h) << 6) + l) * 64;
#pragma unroll
  for (int cf = 0; cf < 4; ++cf)
#pragma unroll
    for (int rf = 0; rf < 4; ++rf) {
      float4 bv = *(const float4*)(rb + (cf << 4) + (rf << 2));
      s[rf][cf][0] += bv.x; s[rf][cf][1] += bv.y;
      s[rf][cf][2] += bv.z; s[rf][cf][3] += bv.w;
    }

  // softmax over m (4 col-frags x 16 lanes)
#pragma unroll
  for (int rf = 0; rf < 4; ++rf) {
#pragma unroll
    for (int r = 0; r < 4; ++r) {
      float m0 = fmaxf(fmaxf(s[rf][0][r], s[rf][1][r]),
                       fmaxf(s[rf][2][r], s[rf][3][r]));
      m0 = fmaxf(m0, __shfl_xor(m0, 1));
      m0 = fmaxf(m0, __shfl_xor(m0, 2));
      m0 = fmaxf(m0, __shfl_xor(m0, 4));
      m0 = fmaxf(m0, __shfl_xor(m0, 8));
      float t0 = 0.f;
#pragma unroll
      for (int cf = 0; cf < 4; ++cf) {
        s[rf][cf][r] = __expf(s[rf][cf][r] - m0);
        t0 += s[rf][cf][r];
      }
      t0 += __shfl_xor(t0, 1);
      t0 += __shfl_xor(t0, 2);
      t0 += __shfl_xor(t0, 4);
      t0 += __shfl_xor(t0, 8);
      const float inv = 1.f / t0;
#pragma unroll
      for (int cf = 0; cf < 4; ++cf) s[rf][cf][r] *= inv;
    }
  }

  // P -> LDS (wave-private; own-wave readback needs no barrier)
#pragma unroll
  for (int rf = 0; rf < 4; ++rf)
#pragma unroll
    for (int r = 0; r < 4; ++r) {
      const int n = (rf << 4) + (g << 2) + r;
#pragma unroll
      for (int cf = 0; cf < 4; ++cf)
        sh.P[wid][n][(cf << 4) + u] = f2b(s[rf][cf][r]);
    }

  // pf fragments into regs (lane-transpose), once for both branches
  bf16x8 pf[4][2];
#pragma unroll
  for (int cf = 0; cf < 4; ++cf)
#pragma unroll
    for (int ks = 0; ks < 2; ++ks)
      pf[cf][ks] = *(const bf16x8*)&sh.P[wid][(cf << 4) + u][(ks << 5) + (g << 3)];

  __syncthreads();  // barrier #1: all waves hold pf -> P space reusable as Xl

  // PV per branch (xt reused -> lower register liveness)
  const u16* vbase = vt + ((size_t)((win << 3) | h) << 11);
#pragma unroll
  for (int br = 0; br < 2; ++br) {
    bf16x8 vf[2][2];
#pragma unroll
    for (int df = 0; df < 2; ++df)
#pragma unroll
      for (int ks = 0; ks < 2; ++ks)
        vf[df][ks] = *(const bf16x8*)(vbase + (size_t)br * 16777216 +
                                      (df << 10) + (ks << 9) + (g << 7) + (u << 3));
    f32x4 xt[2][4];
#pragma unroll
    for (int df = 0; df < 2; ++df)
#pragma unroll
      for (int cf = 0; cf < 4; ++cf) xt[df][cf] = z4;
#pragma unroll
    for (int cf = 0; cf < 4; ++cf)
#pragma unroll
      for (int ks = 0; ks < 2; ++ks) {
        xt[0][cf] = __builtin_amdgcn_mfma_f32_16x16x32_bf16(
            vf[0][ks], pf[cf][ks], xt[0][cf], 0, 0, 0);
        xt[1][cf] = __builtin_amdgcn_mfma_f32_16x16x32_bf16(
            vf[1][ks], pf[cf][ks], xt[1][cf], 0, 0, 0);
      }
    // X -> LDS: tok = cf*16+u, ch = h*32 + df*16 + g*4
#pragma unroll
    for (int df = 0; df < 2; ++df)
#pragma unroll
      for (int cf = 0; cf < 4; ++cf) {
        const int tok = (cf << 4) + u;
        const int ch = (h << 5) + (df << 4) + (g << 2);
        *(u32*)&sh.Xl[br][tok][ch] = pk2(xt[df][cf][0], xt[df][cf][1]);
        *(u32*)&sh.Xl[br][tok][ch + 2] = pk2(xt[df][cf][2], xt[df][cf][3]);
      }
  }
  __syncthreads();  // barrier #2: Xl complete

  // cooperative proj per branch; wave owns oc in [32*wid, 32*wid+32)
#pragma unroll
  for (int br = 0; br < 2; ++br) {
    f32x4 acc[4][2];
#pragma unroll
    for (int mf = 0; mf < 4; ++mf)
#pragma unroll
      for (int cfi = 0; cfi < 2; ++cfi) acc[mf][cfi] = z4;
#pragma unroll
    for (int ks = 0; ks < 8; ++ks) {
      bf16x8 a[4];
#pragma unroll
      for (int mf = 0; mf < 4; ++mf)
        a[mf] = *(const bf16x8*)&sh.Xl[br][(mf << 4) + u][(ks << 5) + (g << 3)];
      bf16x8 bw[2];
#pragma unroll
      for (int cfi = 0; cfi < 2; ++cfi) {
        const int cf = (wid << 1) | cfi;
        bw[cfi] = *(const bf16x8*)(pwf +
            ((((((size_t)(cf << 3) | ks) << 2) | g) << 4 | u) << 3));
      }
#pragma unroll
      for (int mf = 0; mf < 4; ++mf)
#pragma unroll
        for (int cfi = 0; cfi < 2; ++cfi)
          acc[mf][cfi] = __builtin_amdgcn_mfma_f32_16x16x32_bf16(
              a[mf], bw[cfi], acc[mf][cfi], 0, 0, 0);
    }

    // epilogue: +bias, reverse-shift scatter
    float* ob = outp + (size_t)br * 16777216;
#pragma unroll
    for (int cfi = 0; cfi < 2; ++cfi) {
      const int oc = (((wid << 1) | cfi) << 4) + u;
      const float bv = pbias[oc];
#pragma unroll
      for (int mf = 0; mf < 4; ++mf) {
#pragma unroll
        for (int r = 0; r < 4; ++r) {
          const int tok = (mf << 4) + (g << 2) + r;
          const int nhs = (wh << 3) + (tok >> 3);
          const int nws = (ww << 3) + (tok & 7);
          ob[((((size_t)((b << 6) | ((nhs + 4) & 63)) << 6) |
               ((nws + 4) & 63)) << 8) + oc] = acc[mf][cfi][r] + bv;
        }
      }
    }
  }
}

// ---------------------------------------------------------------------------
extern "C" void kernel_launch(void* const* d_in, const int* in_sizes, int n_in,
                              void* d_out, int out_size, void* d_ws,
                              size_t ws_size, hipStream_t stream) {
  (void)in_sizes; (void)n_in; (void)out_size; (void)ws_size;
  const float* q   = (const float*)d_in[0];
  const float* k   = (const float*)d_in[1];
  const float* vs  = (const float*)d_in[2];
  const float* vsh = (const float*)d_in[3];
  const float* kW  = (const float*)d_in[4];
  const float* kb  = (const float*)d_in[5];
  const float* vWs = (const float*)d_in[6];
  const float* vbs = (const float*)d_in[7];
  const float* vWh = (const float*)d_in[8];
  const float* vbh = (const float*)d_in[9];
  const float* pW  = (const float*)d_in[10];
  const float* pb  = (const float*)d_in[11];
  const float* rpb = (const float*)d_in[12];
  float* out = (float*)d_out;

  float* f = (float*)d_ws;
  float* qps = f;                       // 262144
  float* qpq = f + 262144;              // 262144
  float* kps = f + 524288;              // 262144
  float* kpq = f + 786432;              // 262144
  float* qA  = f + 1048576;
  float* qB  = f + 1052672;
  float* kA  = f + 1056768;
  float* kB  = f + 1060864;
  float* rpbm = f + 1064960;            // 131072 floats
  u16* wfall = (u16*)(f + 1196032);     // 4 x 65536 u16 = 131072 floats
  u16* klin  = (u16*)(f + 1327104);     // 16.77M u16 = 8388608 floats
  u16* vt    = (u16*)(f + 9715712);     // 33.55M u16 (2 branches)
  u16* pwf   = wfall + 3 * 65536;

  stats_f32<<<1024, 256, 0, stream>>>(q, qps, qpq);
  finalize_stats<<<16, 256, 0, stream>>>(qps, qpq, qA, qB,
                                         0.17677669529663687f);  // 1/sqrt(32)
  rpbm_prep<<<512, 256, 0, stream>>>(rpb, rpbm);
  wf_prep<<<dim3(32, 4), 256, 0, stream>>>(kW, vWs, vWh, pW, wfall);

  gemm_fullk<<<dim3(1024, 3), 256, 0, stream>>>(k, vs, vsh, wfall,
                                                kb, vbs, vbh,
                                                klin, vt, kps, kpq);
  finalize_stats<<<16, 256, 0, stream>>>(kps, kpq, kA, kB, 1.0f);

  attn_mega<<<1024, 512, 0, stream>>>(q, qA, qB, klin, kA, kB, vt, rpbm,
                                      pwf, pb, out);
}

// Round 15
// 194.847 us; speedup vs baseline: 1.2223x; 1.0188x over previous
//
#include <hip/hip_runtime.h>

// ============================================================================
// ShiftedWindowAttention — bf16 MFMA pipeline, v15.
// B=16,H=W=64,C=256,NH=8,HD=32, win 8x8 (N=64), shift 4 -> 1024 windows.
//
// stats_f32 -> finalize(q) -> rpbm -> wf_prep(4 weights) ->
// gemm_fullk (k+v_s+v_sh; BM=64 full-K LDS panel, 1 barrier, 4 waves) ->
// finalize(k) -> attn_mega.
//
// Round-15: v13/v14 gemm stuck at VGPR=68 -> compiler re-serialized the
// va[16] staging batch (64 VGPRs of payload can't fit a 68-reg allocation).
// Fix: __launch_bounds__(256, 4) = min 4 waves/EU = VGPR cap 128 (4 blk/CU,
// which is already our LDS limit -> zero occupancy cost, 4x deeper staging).
// ============================================================================

typedef unsigned short u16;
typedef unsigned int u32;
typedef __attribute__((ext_vector_type(8))) short bf16x8;   // 8 bf16 = 4 VGPR
typedef __attribute__((ext_vector_type(4))) float f32x4;

__device__ __forceinline__ float b2f(u16 u) {
  return __uint_as_float(((u32)u) << 16);
}
// native conversion -> v_cvt_pk_bf16_f32 (RNE)
__device__ __forceinline__ u16 f2b(float f) {
  return __builtin_bit_cast(u16, (__bf16)f);
}
__device__ __forceinline__ u32 pk2(float a, float b) {
  return (u32)f2b(a) | ((u32)f2b(b) << 16);
}
__device__ __forceinline__ bf16x8 pk8(float4 v0, float4 v1) {
  uint4 w;
  w.x = pk2(v0.x, v0.y); w.y = pk2(v0.z, v0.w);
  w.z = pk2(v1.x, v1.y); w.w = pk2(v1.z, v1.w);
  return __builtin_bit_cast(bf16x8, w);
}

// ---------------------------------------------------------------------------
// q stats, atomic-free partials.
// ---------------------------------------------------------------------------
__global__ __launch_bounds__(256) void stats_f32(const float* __restrict__ src,
                                                 float* __restrict__ ps,
                                                 float* __restrict__ pq) {
  const int blk = blockIdx.x;          // 1024 = b(16) * chunk(64)
  const int b = blk >> 6;
  const int p0 = (blk & 63) << 6;
  const int c = threadIdx.x;
  const float* p = src + (((size_t)(b << 12) + p0) << 8) + c;
  float s = 0.f, sq = 0.f;
#pragma unroll 8
  for (int i = 0; i < 64; ++i) {
    float v = p[(size_t)i << 8];
    s += v;
    sq = fmaf(v, v, sq);
  }
  ps[(blk << 8) + c] = s;
  pq[(blk << 8) + c] = sq;
}

__global__ void finalize_stats(const float* __restrict__ ps,
                               const float* __restrict__ pq,
                               float* __restrict__ A, float* __restrict__ Bo,
                               float scale) {
  const int i = blockIdx.x * 256 + threadIdx.x;  // 4096
  const int b = i >> 8, c = i & 255;
  const float* s0 = ps + ((size_t)(b << 6) << 8) + c;
  const float* q0 = pq + ((size_t)(b << 6) << 8) + c;
  float s = 0.f, sq = 0.f;
#pragma unroll 8
  for (int j = 0; j < 64; ++j) {
    s += s0[(size_t)j << 8];
    sq += q0[(size_t)j << 8];
  }
  float m = s * (1.f / 4096.f);
  float v = sq * (1.f / 4096.f) - m * m;
  float a = rsqrtf(v + 1e-5f) * scale;
  A[i] = a;
  Bo[i] = -m * a;
}

// ---------------------------------------------------------------------------
// rpb + mask fused, MFMA D-fragment order.
// ---------------------------------------------------------------------------
__global__ __launch_bounds__(256) void rpbm_prep(const float* __restrict__ rpb,
                                                 float* __restrict__ rpbm) {
  const int idx = blockIdx.x * 256 + threadIdx.x;  // 131072
  const int t = idx & 63;
  const int lane = (idx >> 6) & 63;
  const int h = (idx >> 12) & 7;
  const int var = idx >> 15;
  const int cf = t >> 4, rf = (t >> 2) & 3, r = t & 3;
  const int n = ((lane >> 4) << 2) + r + (rf << 4);
  const int m = (lane & 15) + (cf << 4);
  const int vh = var >> 1, vw = var & 1;
  const int ln = (vh ? (1 + ((n >> 3) >= 4)) : 0) * 3 + (vw ? (1 + ((n & 7) >= 4)) : 0);
  const int lm = (vh ? (1 + ((m >> 3) >= 4)) : 0) * 3 + (vw ? (1 + ((m & 7) >= 4)) : 0);
  rpbm[idx] = rpb[(h << 12) + (n << 6) + m] + ((ln == lm) ? 0.f : -100.f);
}

// ---------------------------------------------------------------------------
// All weights -> bf16 fragment order wf[w][cf][ks][g][u][8]:
// oc = cf*16+u, ic = ks*32+g*8+j.  w: 0=kW 1=vWs 2=vWh 3=pW.
// Per-weight block = 8192 fragments x 8 u16 = 65536 u16.
// ---------------------------------------------------------------------------
__global__ __launch_bounds__(256) void wf_prep(const float* __restrict__ w0,
                                               const float* __restrict__ w1,
                                               const float* __restrict__ w2,
                                               const float* __restrict__ w3,
                                               u16* __restrict__ wf) {
  const int idx = blockIdx.x * 256 + threadIdx.x;  // 8192 per weight
  const int u_ = idx & 15, g_ = (idx >> 4) & 3, ks_ = (idx >> 6) & 7,
            cf_ = idx >> 9;
  const int oc = (cf_ << 4) + u_, ic = (ks_ << 5) + (g_ << 3);
  const float* srcs[4] = {w0, w1, w2, w3};
  const float* p = srcs[blockIdx.y] + (size_t)oc * 256 + ic;
  float4 v0 = *(const float4*)p;
  float4 v1 = *(const float4*)(p + 4);
  *(bf16x8*)(wf + (size_t)blockIdx.y * 65536 + (size_t)idx * 8) = pk8(v0, v1);
}

// ---------------------------------------------------------------------------
// Full-K stage-once GEMM, BM=64 (one window per block):
// dst = gather_window_shift(src) @ W^T + bias, bf16 out, fragment order.
// Block = 256 thr = 4 waves (wave wc owns cols [64wc,64wc+64), all 64 rows),
// K=256 staged once (A_s[64][264] bf16, 33.8KB -> 4 blocks/CU). ONE barrier.
// W-fragments direct from L2-resident wf. grid (1024, 3).
// __launch_bounds__(256,4): VGPR cap 128 so the va[16] staging batch stays
// batched (v13/v14: default allocation chose 68 regs -> serialized loads).
// ---------------------------------------------------------------------------
__global__ __launch_bounds__(256, 4) void gemm_fullk(
    const float* __restrict__ ksrc, const float* __restrict__ vs,
    const float* __restrict__ vsh, const u16* __restrict__ wf,
    const float* __restrict__ kbias, const float* __restrict__ vbs,
    const float* __restrict__ vbh, u16* __restrict__ klin,
    u16* __restrict__ vt, float* __restrict__ kps, float* __restrict__ kpq) {
  const int mode = blockIdx.y;
  const float* src;
  const float* bias;
  u16* dst;
  if (mode == 0)      { src = ksrc; bias = kbias; dst = klin; }
  else if (mode == 1) { src = vs;   bias = vbs;  dst = vt; }
  else                { src = vsh;  bias = vbh;  dst = vt + 16777216; }
  const u16* wfm = wf + (size_t)mode * 65536;

  __shared__ u16 A_s[64][264];
  const int t = threadIdx.x;
  const int bx = blockIdx.x;   // = window
  const int win = bx;

  // ---- stage A panel: 4 thr/row, 64 f32 each, all 16 loads in flight ----
  {
    const int row = t >> 2;           // 0..63 (token in window)
    const int c0 = (t & 3) << 6;
    const int rg = (bx << 6) + row;
    const int bb = rg >> 12, rr = rg & 4095, wi = rr >> 6, nn = rr & 63;
    const int hs = ((wi >> 3) << 3) + (nn >> 3);
    const int wsq = ((wi & 7) << 3) + (nn & 7);
    const float* ap = src +
        ((((size_t)((bb << 6) | ((hs + 4) & 63)) << 6) | ((wsq + 4) & 63)) << 8) + c0;
    float4 va[16];
#pragma unroll
    for (int q = 0; q < 16; ++q) va[q] = *(const float4*)(ap + (q << 2));
#pragma unroll
    for (int q = 0; q < 8; ++q)
      *(bf16x8*)&A_s[row][c0 + (q << 3)] = pk8(va[2 * q], va[2 * q + 1]);
  }
  __syncthreads();  // the only barrier

  const int wc = t >> 6, l = t & 63, u = l & 15, g = l >> 4;

  f32x4 acc[4][4];
#pragma unroll
  for (int i = 0; i < 4; ++i)
#pragma unroll
    for (int j = 0; j < 4; ++j) acc[i][j] = {0.f, 0.f, 0.f, 0.f};

#pragma unroll
  for (int ks = 0; ks < 8; ++ks) {
    bf16x8 bfr[4];
#pragma unroll
    for (int cf = 0; cf < 4; ++cf)
      bfr[cf] = *(const bf16x8*)(wfm +
          ((((size_t)(((wc << 2) | cf) << 3) | ks) << 2 | g) << 4 | u) * 8);
    bf16x8 a[4];
#pragma unroll
    for (int rf = 0; rf < 4; ++rf)
      a[rf] = *(const bf16x8*)&A_s[(rf << 4) + u][(ks << 5) + (g << 3)];
#pragma unroll
    for (int rf = 0; rf < 4; ++rf)
#pragma unroll
      for (int cf = 0; cf < 4; ++cf)
        acc[rf][cf] = __builtin_amdgcn_mfma_f32_16x16x32_bf16(a[rf], bfr[cf],
                                                              acc[rf][cf], 0, 0, 0);
  }

  // ---- epilogue: fragment-order stores (+ fused k-stats for mode 0) ----
#pragma unroll
  for (int cf = 0; cf < 4; ++cf) {
    const int col = (wc << 6) + (cf << 4) + u;
    const float bv = bias[col];
    float s = 0.f, sq = 0.f;
#pragma unroll
    for (int rf = 0; rf < 4; ++rf) {
      if (mode == 0) {
        // klin: [win][h][cf_tok][g][u][8j]; token = (rf<<4)+(g<<2)+r, ch=col
        const int hh = col >> 5;
        const int ga = (col >> 3) & 3;
        const int j = col & 7;
        const size_t base =
            ((size_t)((win << 3) | hh) << 11) + (rf << 9) + (ga << 7) + j;
#pragma unroll
        for (int r = 0; r < 4; ++r) {
          u16 hv = f2b(acc[rf][cf][r] + bv);
          dst[base + (((g << 2) + r) << 3)] = hv;
          float rv = b2f(hv);
          s += rv;
          sq = fmaf(rv, rv, sq);
        }
      } else {
        // vt: [win][h][df][ks][g][u][8j]; d-ch = col, token = (rf<<4)+(g<<2)+r
        const int hh = col >> 5;
        const int df = (col >> 4) & 1;
        const int ks_ = rf >> 1;
        const int ga = ((rf & 1) << 1) | (g >> 1);
        const size_t base = ((size_t)((win << 3) | hh) << 11) + (df << 10) +
                            (ks_ << 9) + (ga << 7) + (u << 3) + ((g & 1) << 2);
        u32 w0 = pk2(acc[rf][cf][0] + bv, acc[rf][cf][1] + bv);
        u32 w1 = pk2(acc[rf][cf][2] + bv, acc[rf][cf][3] + bv);
        *(uint2*)(dst + base) = make_uint2(w0, w1);
      }
    }
    if (mode == 0) {
      s += __shfl_xor(s, 16);
      s += __shfl_xor(s, 32);
      sq += __shfl_xor(sq, 16);
      sq += __shfl_xor(sq, 32);
      if (g == 0) {
        kps[(win << 8) + col] = s;
        kpq[(win << 8) + col] = sq;
      }
    }
  }
}

// ---------------------------------------------------------------------------
// Fused attention + projection (unchanged from v13/v14). Block = window
// (1024), 512 thr = 8 waves, wave = head. 2 barriers. Strides P=72, Xl=264.
// ---------------------------------------------------------------------------
union AttnSh {
  u16 P[8][64][72];     // 73728 B
  u16 Xl[2][64][264];   // 67584 B
};

__global__ __launch_bounds__(512) void attn_mega(
    const float* __restrict__ qsrc, const float* __restrict__ qA_,
    const float* __restrict__ qB_, const u16* __restrict__ klin,
    const float* __restrict__ kA_, const float* __restrict__ kB_,
    const u16* __restrict__ vt, const float* __restrict__ rpbm,
    const u16* __restrict__ pwf, const float* __restrict__ pbias,
    float* __restrict__ outp) {
  __shared__ AttnSh sh;
  const int tid = threadIdx.x;
  const int wid = tid >> 6;      // head
  const int l = tid & 63;
  const int u = l & 15;
  const int g = l >> 4;
  const int win = blockIdx.x;
  const int h = wid;
  const int b = win >> 6;
  const int wIdx = win & 63;
  const int wh = wIdx >> 3, ww = wIdx & 7;
  const int var = ((wh == 7) ? 2 : 0) | ((ww == 7) ? 1 : 0);
  const int coff = (h << 5) + (g << 3);

  float qav[8], qbv[8], kav[8], kbv[8];
  {
    const int o = (b << 8) + coff;
    float4 a0 = *(const float4*)(qA_ + o), a1 = *(const float4*)(qA_ + o + 4);
    float4 b0 = *(const float4*)(qB_ + o), b1 = *(const float4*)(qB_ + o + 4);
    float4 c0v = *(const float4*)(kA_ + o), c1 = *(const float4*)(kA_ + o + 4);
    float4 d0v = *(const float4*)(kB_ + o), d1 = *(const float4*)(kB_ + o + 4);
    qav[0]=a0.x;qav[1]=a0.y;qav[2]=a0.z;qav[3]=a0.w;qav[4]=a1.x;qav[5]=a1.y;qav[6]=a1.z;qav[7]=a1.w;
    qbv[0]=b0.x;qbv[1]=b0.y;qbv[2]=b0.z;qbv[3]=b0.w;qbv[4]=b1.x;qbv[5]=b1.y;qbv[6]=b1.z;qbv[7]=b1.w;
    kav[0]=c0v.x;kav[1]=c0v.y;kav[2]=c0v.z;kav[3]=c0v.w;kav[4]=c1.x;kav[5]=c1.y;kav[6]=c1.z;kav[7]=c1.w;
    kbv[0]=d0v.x;kbv[1]=d0v.y;kbv[2]=d0v.z;kbv[3]=d0v.w;kbv[4]=d1.x;kbv[5]=d1.y;kbv[6]=d1.z;kbv[7]=d1.w;
  }

  // q fragments (gathered + normalized + scaled)
  bf16x8 qf[4];
#pragma unroll
  for (int rf = 0; rf < 4; ++rf) {
    const int n = (rf << 4) + u;
    const int nhs = (wh << 3) + (n >> 3);
    const int nws = (ww << 3) + (n & 7);
    const float* qp = qsrc +
        ((((size_t)((b << 6) | ((nhs + 4) & 63)) << 6) | ((nws + 4) & 63)) << 8) + coff;
    float4 v0 = *(const float4*)qp;
    float4 v1 = *(const float4*)(qp + 4);
    float qv[8] = {v0.x, v0.y, v0.z, v0.w, v1.x, v1.y, v1.z, v1.w};
#pragma unroll
    for (int j = 0; j < 8; ++j) qf[rf][j] = (short)f2b(fmaf(qv[j], qav[j], qbv[j]));
  }

  // k fragments — fragment-ordered klin: wave read = 64 lanes x 16B contiguous
  const u16* kp = klin + ((size_t)((win << 3) | h) << 11);
  bf16x8 kf[4];
#pragma unroll
  for (int cf = 0; cf < 4; ++cf) {
    union { uint4 v; u16 s[8]; } raw;
    raw.v = *(const uint4*)(kp + (cf << 9) + (g << 7) + (u << 3));
#pragma unroll
    for (int j = 0; j < 8; ++j)
      kf[cf][j] = (short)f2b(fmaf(b2f(raw.s[j]), kav[j], kbv[j]));
  }

  // S = q k^T
  f32x4 s[4][4];
  const f32x4 z4 = {0.f, 0.f, 0.f, 0.f};
#pragma unroll
  for (int rf = 0; rf < 4; ++rf)
#pragma unroll
    for (int cf = 0; cf < 4; ++cf)
      s[rf][cf] = __builtin_amdgcn_mfma_f32_16x16x32_bf16(qf[rf], kf[cf], z4, 0, 0, 0);

  // + rpb + mask (pre-fused, fragment order)
  const float* rb = rpbm + ((((var << 3) + h) << 6) + l) * 64;
#pragma unroll
  for (int cf = 0; cf < 4; ++cf)
#pragma unroll
    for (int rf = 0; rf < 4; ++rf) {
      float4 bv = *(const float4*)(rb + (cf << 4) + (rf << 2));
      s[rf][cf][0] += bv.x; s[rf][cf][1] += bv.y;
      s[rf][cf][2] += bv.z; s[rf][cf][3] += bv.w;
    }

  // softmax over m (4 col-frags x 16 lanes)
#pragma unroll
  for (int rf = 0; rf < 4; ++rf) {
#pragma unroll
    for (int r = 0; r < 4; ++r) {
      float m0 = fmaxf(fmaxf(s[rf][0][r], s[rf][1][r]),
                       fmaxf(s[rf][2][r], s[rf][3][r]));
      m0 = fmaxf(m0, __shfl_xor(m0, 1));
      m0 = fmaxf(m0, __shfl_xor(m0, 2));
      m0 = fmaxf(m0, __shfl_xor(m0, 4));
      m0 = fmaxf(m0, __shfl_xor(m0, 8));
      float t0 = 0.f;
#pragma unroll
      for (int cf = 0; cf < 4; ++cf) {
        s[rf][cf][r] = __expf(s[rf][cf][r] - m0);
        t0 += s[rf][cf][r];
      }
      t0 += __shfl_xor(t0, 1);
      t0 += __shfl_xor(t0, 2);
      t0 += __shfl_xor(t0, 4);
      t0 += __shfl_xor(t0, 8);
      const float inv = 1.f / t0;
#pragma unroll
      for (int cf = 0; cf < 4; ++cf) s[rf][cf][r] *= inv;
    }
  }

  // P -> LDS (wave-private; own-wave readback needs no barrier)
#pragma unroll
  for (int rf = 0; rf < 4; ++rf)
#pragma unroll
    for (int r = 0; r < 4; ++r) {
      const int n = (rf << 4) + (g << 2) + r;
#pragma unroll
      for (int cf = 0; cf < 4; ++cf)
        sh.P[wid][n][(cf << 4) + u] = f2b(s[rf][cf][r]);
    }

  // pf fragments into regs (lane-transpose), once for both branches
  bf16x8 pf[4][2];
#pragma unroll
  for (int cf = 0; cf < 4; ++cf)
#pragma unroll
    for (int ks = 0; ks < 2; ++ks)
      pf[cf][ks] = *(const bf16x8*)&sh.P[wid][(cf << 4) + u][(ks << 5) + (g << 3)];

  __syncthreads();  // barrier #1: all waves hold pf -> P space reusable as Xl

  // PV per branch (xt reused -> lower register liveness)
  const u16* vbase = vt + ((size_t)((win << 3) | h) << 11);
#pragma unroll
  for (int br = 0; br < 2; ++br) {
    bf16x8 vf[2][2];
#pragma unroll
    for (int df = 0; df < 2; ++df)
#pragma unroll
      for (int ks = 0; ks < 2; ++ks)
        vf[df][ks] = *(const bf16x8*)(vbase + (size_t)br * 16777216 +
                                      (df << 10) + (ks << 9) + (g << 7) + (u << 3));
    f32x4 xt[2][4];
#pragma unroll
    for (int df = 0; df < 2; ++df)
#pragma unroll
      for (int cf = 0; cf < 4; ++cf) xt[df][cf] = z4;
#pragma unroll
    for (int cf = 0; cf < 4; ++cf)
#pragma unroll
      for (int ks = 0; ks < 2; ++ks) {
        xt[0][cf] = __builtin_amdgcn_mfma_f32_16x16x32_bf16(
            vf[0][ks], pf[cf][ks], xt[0][cf], 0, 0, 0);
        xt[1][cf] = __builtin_amdgcn_mfma_f32_16x16x32_bf16(
            vf[1][ks], pf[cf][ks], xt[1][cf], 0, 0, 0);
      }
    // X -> LDS: tok = cf*16+u, ch = h*32 + df*16 + g*4
#pragma unroll
    for (int df = 0; df < 2; ++df)
#pragma unroll
      for (int cf = 0; cf < 4; ++cf) {
        const int tok = (cf << 4) + u;
        const int ch = (h << 5) + (df << 4) + (g << 2);
        *(u32*)&sh.Xl[br][tok][ch] = pk2(xt[df][cf][0], xt[df][cf][1]);
        *(u32*)&sh.Xl[br][tok][ch + 2] = pk2(xt[df][cf][2], xt[df][cf][3]);
      }
  }
  __syncthreads();  // barrier #2: Xl complete

  // cooperative proj per branch; wave owns oc in [32*wid, 32*wid+32)
#pragma unroll
  for (int br = 0; br < 2; ++br) {
    f32x4 acc[4][2];
#pragma unroll
    for (int mf = 0; mf < 4; ++mf)
#pragma unroll
      for (int cfi = 0; cfi < 2; ++cfi) acc[mf][cfi] = z4;
#pragma unroll
    for (int ks = 0; ks < 8; ++ks) {
      bf16x8 a[4];
#pragma unroll
      for (int mf = 0; mf < 4; ++mf)
        a[mf] = *(const bf16x8*)&sh.Xl[br][(mf << 4) + u][(ks << 5) + (g << 3)];
      bf16x8 bw[2];
#pragma unroll
      for (int cfi = 0; cfi < 2; ++cfi) {
        const int cf = (wid << 1) | cfi;
        bw[cfi] = *(const bf16x8*)(pwf +
            ((((((size_t)(cf << 3) | ks) << 2) | g) << 4 | u) << 3));
      }
#pragma unroll
      for (int mf = 0; mf < 4; ++mf)
#pragma unroll
        for (int cfi = 0; cfi < 2; ++cfi)
          acc[mf][cfi] = __builtin_amdgcn_mfma_f32_16x16x32_bf16(
              a[mf], bw[cfi], acc[mf][cfi], 0, 0, 0);
    }

    // epilogue: +bias, reverse-shift scatter
    float* ob = outp + (size_t)br * 16777216;
#pragma unroll
    for (int cfi = 0; cfi < 2; ++cfi) {
      const int oc = (((wid << 1) | cfi) << 4) + u;
      const float bv = pbias[oc];
#pragma unroll
      for (int mf = 0; mf < 4; ++mf) {
#pragma unroll
        for (int r = 0; r < 4; ++r) {
          const int tok = (mf << 4) + (g << 2) + r;
          const int nhs = (wh << 3) + (tok >> 3);
          const int nws = (ww << 3) + (tok & 7);
          ob[((((size_t)((b << 6) | ((nhs + 4) & 63)) << 6) |
               ((nws + 4) & 63)) << 8) + oc] = acc[mf][cfi][r] + bv;
        }
      }
    }
  }
}

// ---------------------------------------------------------------------------
extern "C" void kernel_launch(void* const* d_in, const int* in_sizes, int n_in,
                              void* d_out, int out_size, void* d_ws,
                              size_t ws_size, hipStream_t stream) {
  (void)in_sizes; (void)n_in; (void)out_size; (void)ws_size;
  const float* q   = (const float*)d_in[0];
  const float* k   = (const float*)d_in[1];
  const float* vs  = (const float*)d_in[2];
  const float* vsh = (const float*)d_in[3];
  const float* kW  = (const float*)d_in[4];
  const float* kb  = (const float*)d_in[5];
  const float* vWs = (const float*)d_in[6];
  const float* vbs = (const float*)d_in[7];
  const float* vWh = (const float*)d_in[8];
  const float* vbh = (const float*)d_in[9];
  const float* pW  = (const float*)d_in[10];
  const float* pb  = (const float*)d_in[11];
  const float* rpb = (const float*)d_in[12];
  float* out = (float*)d_out;

  float* f = (float*)d_ws;
  float* qps = f;                       // 262144
  float* qpq = f + 262144;              // 262144
  float* kps = f + 524288;              // 262144
  float* kpq = f + 786432;              // 262144
  float* qA  = f + 1048576;
  float* qB  = f + 1052672;
  float* kA  = f + 1056768;
  float* kB  = f + 1060864;
  float* rpbm = f + 1064960;            // 131072 floats
  u16* wfall = (u16*)(f + 1196032);     // 4 x 65536 u16 = 131072 floats
  u16* klin  = (u16*)(f + 1327104);     // 16.77M u16 = 8388608 floats
  u16* vt    = (u16*)(f + 9715712);     // 33.55M u16 (2 branches)
  u16* pwf   = wfall + 3 * 65536;

  stats_f32<<<1024, 256, 0, stream>>>(q, qps, qpq);
  finalize_stats<<<16, 256, 0, stream>>>(qps, qpq, qA, qB,
                                         0.17677669529663687f);  // 1/sqrt(32)
  rpbm_prep<<<512, 256, 0, stream>>>(rpb, rpbm);
  wf_prep<<<dim3(32, 4), 256, 0, stream>>>(kW, vWs, vWh, pW, wfall);

  gemm_fullk<<<dim3(1024, 3), 256, 0, stream>>>(k, vs, vsh, wfall,
                                                kb, vbs, vbh,
                                                klin, vt, kps, kpq);
  finalize_stats<<<16, 256, 0, stream>>>(kps, kpq, kA, kB, 1.0f);

  attn_mega<<<1024, 512, 0, stream>>>(q, qA, qB, klin, kA, kB, vt, rpbm,
                                      pwf, pb, out);
}

// Round 16
// 189.346 us; speedup vs baseline: 1.2579x; 1.0291x over previous
//
#include <hip/hip_runtime.h>

// ============================================================================
// ShiftedWindowAttention — bf16 MFMA pipeline, v16.
// B=16,H=W=64,C=256,NH=8,HD=32, win 8x8 (N=64), shift 4 -> 1024 windows.
//
// stats_f32 -> finalize(q) -> rpbm -> wf_prep(4 weights) ->
// gemm_fullk (k+v_s+v_sh; BM=64 full-K LDS panel, 1 barrier) ->
// finalize(k) -> attn_mega.
//
// Round-16: v13-v15 staging map (4 thr/row, 256B lane stride) made every
// load instruction touch 64 distinct 64B lines for 1KB of data (4x request
// amplification; HBM stuck at 2.3TB/s). New map: one token row (1KB) per
// wave-instruction — lane lj reads float4 at byte lj*16 (fully coalesced,
// wave-uniform base), 16 rows/wave over 16 independent iterations;
// ds_write_b64 per lane (512B/row, minimal banking).
// ============================================================================

typedef unsigned short u16;
typedef unsigned int u32;
typedef __attribute__((ext_vector_type(8))) short bf16x8;   // 8 bf16 = 4 VGPR
typedef __attribute__((ext_vector_type(4))) float f32x4;

__device__ __forceinline__ float b2f(u16 u) {
  return __uint_as_float(((u32)u) << 16);
}
// native conversion -> v_cvt_pk_bf16_f32 (RNE)
__device__ __forceinline__ u16 f2b(float f) {
  return __builtin_bit_cast(u16, (__bf16)f);
}
__device__ __forceinline__ u32 pk2(float a, float b) {
  return (u32)f2b(a) | ((u32)f2b(b) << 16);
}
__device__ __forceinline__ bf16x8 pk8(float4 v0, float4 v1) {
  uint4 w;
  w.x = pk2(v0.x, v0.y); w.y = pk2(v0.z, v0.w);
  w.z = pk2(v1.x, v1.y); w.w = pk2(v1.z, v1.w);
  return __builtin_bit_cast(bf16x8, w);
}

// ---------------------------------------------------------------------------
// q stats, atomic-free partials.
// ---------------------------------------------------------------------------
__global__ __launch_bounds__(256) void stats_f32(const float* __restrict__ src,
                                                 float* __restrict__ ps,
                                                 float* __restrict__ pq) {
  const int blk = blockIdx.x;          // 1024 = b(16) * chunk(64)
  const int b = blk >> 6;
  const int p0 = (blk & 63) << 6;
  const int c = threadIdx.x;
  const float* p = src + (((size_t)(b << 12) + p0) << 8) + c;
  float s = 0.f, sq = 0.f;
#pragma unroll 8
  for (int i = 0; i < 64; ++i) {
    float v = p[(size_t)i << 8];
    s += v;
    sq = fmaf(v, v, sq);
  }
  ps[(blk << 8) + c] = s;
  pq[(blk << 8) + c] = sq;
}

__global__ void finalize_stats(const float* __restrict__ ps,
                               const float* __restrict__ pq,
                               float* __restrict__ A, float* __restrict__ Bo,
                               float scale) {
  const int i = blockIdx.x * 256 + threadIdx.x;  // 4096
  const int b = i >> 8, c = i & 255;
  const float* s0 = ps + ((size_t)(b << 6) << 8) + c;
  const float* q0 = pq + ((size_t)(b << 6) << 8) + c;
  float s = 0.f, sq = 0.f;
#pragma unroll 8
  for (int j = 0; j < 64; ++j) {
    s += s0[(size_t)j << 8];
    sq += q0[(size_t)j << 8];
  }
  float m = s * (1.f / 4096.f);
  float v = sq * (1.f / 4096.f) - m * m;
  float a = rsqrtf(v + 1e-5f) * scale;
  A[i] = a;
  Bo[i] = -m * a;
}

// ---------------------------------------------------------------------------
// rpb + mask fused, MFMA D-fragment order.
// ---------------------------------------------------------------------------
__global__ __launch_bounds__(256) void rpbm_prep(const float* __restrict__ rpb,
                                                 float* __restrict__ rpbm) {
  const int idx = blockIdx.x * 256 + threadIdx.x;  // 131072
  const int t = idx & 63;
  const int lane = (idx >> 6) & 63;
  const int h = (idx >> 12) & 7;
  const int var = idx >> 15;
  const int cf = t >> 4, rf = (t >> 2) & 3, r = t & 3;
  const int n = ((lane >> 4) << 2) + r + (rf << 4);
  const int m = (lane & 15) + (cf << 4);
  const int vh = var >> 1, vw = var & 1;
  const int ln = (vh ? (1 + ((n >> 3) >= 4)) : 0) * 3 + (vw ? (1 + ((n & 7) >= 4)) : 0);
  const int lm = (vh ? (1 + ((m >> 3) >= 4)) : 0) * 3 + (vw ? (1 + ((m & 7) >= 4)) : 0);
  rpbm[idx] = rpb[(h << 12) + (n << 6) + m] + ((ln == lm) ? 0.f : -100.f);
}

// ---------------------------------------------------------------------------
// All weights -> bf16 fragment order wf[w][cf][ks][g][u][8]:
// oc = cf*16+u, ic = ks*32+g*8+j.  w: 0=kW 1=vWs 2=vWh 3=pW.
// Per-weight block = 8192 fragments x 8 u16 = 65536 u16.
// ---------------------------------------------------------------------------
__global__ __launch_bounds__(256) void wf_prep(const float* __restrict__ w0,
                                               const float* __restrict__ w1,
                                               const float* __restrict__ w2,
                                               const float* __restrict__ w3,
                                               u16* __restrict__ wf) {
  const int idx = blockIdx.x * 256 + threadIdx.x;  // 8192 per weight
  const int u_ = idx & 15, g_ = (idx >> 4) & 3, ks_ = (idx >> 6) & 7,
            cf_ = idx >> 9;
  const int oc = (cf_ << 4) + u_, ic = (ks_ << 5) + (g_ << 3);
  const float* srcs[4] = {w0, w1, w2, w3};
  const float* p = srcs[blockIdx.y] + (size_t)oc * 256 + ic;
  float4 v0 = *(const float4*)p;
  float4 v1 = *(const float4*)(p + 4);
  *(bf16x8*)(wf + (size_t)blockIdx.y * 65536 + (size_t)idx * 8) = pk8(v0, v1);
}

// ---------------------------------------------------------------------------
// Full-K stage-once GEMM, BM=64 (one window per block):
// dst = gather_window_shift(src) @ W^T + bias, bf16 out, fragment order.
// Block = 256 thr = 4 waves (wave wc owns cols [64wc,64wc+64), all 64 rows),
// K=256 staged once (A_s[64][264] bf16, 33.8KB -> 4 blocks/CU). ONE barrier.
// Staging: one 1KB token-row per wave-instruction, fully coalesced.
// W-fragments direct from L2-resident wf. grid (1024, 3).
// ---------------------------------------------------------------------------
__global__ __launch_bounds__(256, 4) void gemm_fullk(
    const float* __restrict__ ksrc, const float* __restrict__ vs,
    const float* __restrict__ vsh, const u16* __restrict__ wf,
    const float* __restrict__ kbias, const float* __restrict__ vbs,
    const float* __restrict__ vbh, u16* __restrict__ klin,
    u16* __restrict__ vt, float* __restrict__ kps, float* __restrict__ kpq) {
  const int mode = blockIdx.y;
  const float* src;
  const float* bias;
  u16* dst;
  if (mode == 0)      { src = ksrc; bias = kbias; dst = klin; }
  else if (mode == 1) { src = vs;   bias = vbs;  dst = vt; }
  else                { src = vsh;  bias = vbh;  dst = vt + 16777216; }
  const u16* wfm = wf + (size_t)mode * 65536;

  __shared__ u16 A_s[64][264];
  const int t = threadIdx.x;
  const int bx = blockIdx.x;   // = window
  const int win = bx;

  // ---- stage A panel: wave stages 16 rows; per row the whole wave reads
  //      1KB contiguous (lane lj -> float4 at byte lj*16) ----
  {
    const int wv = t >> 6;
    const int lj = t & 63;
#pragma unroll
    for (int it = 0; it < 16; ++it) {
      const int row = (wv << 4) + it;    // token in window
      const int rg = (bx << 6) + row;
      const int bb = rg >> 12, rr = rg & 4095, wi = rr >> 6, nn = rr & 63;
      const int hs = ((wi >> 3) << 3) + (nn >> 3);
      const int wsq = ((wi & 7) << 3) + (nn & 7);
      const float* ap = src +
          ((((size_t)((bb << 6) | ((hs + 4) & 63)) << 6) | ((wsq + 4) & 63)) << 8) +
          (lj << 2);
      float4 v = *(const float4*)ap;
      *(uint2*)&A_s[row][lj << 2] = make_uint2(pk2(v.x, v.y), pk2(v.z, v.w));
    }
  }
  __syncthreads();  // the only barrier

  const int wc = t >> 6, l = t & 63, u = l & 15, g = l >> 4;

  f32x4 acc[4][4];
#pragma unroll
  for (int i = 0; i < 4; ++i)
#pragma unroll
    for (int j = 0; j < 4; ++j) acc[i][j] = {0.f, 0.f, 0.f, 0.f};

#pragma unroll
  for (int ks = 0; ks < 8; ++ks) {
    bf16x8 bfr[4];
#pragma unroll
    for (int cf = 0; cf < 4; ++cf)
      bfr[cf] = *(const bf16x8*)(wfm +
          ((((size_t)(((wc << 2) | cf) << 3) | ks) << 2 | g) << 4 | u) * 8);
    bf16x8 a[4];
#pragma unroll
    for (int rf = 0; rf < 4; ++rf)
      a[rf] = *(const bf16x8*)&A_s[(rf << 4) + u][(ks << 5) + (g << 3)];
#pragma unroll
    for (int rf = 0; rf < 4; ++rf)
#pragma unroll
      for (int cf = 0; cf < 4; ++cf)
        acc[rf][cf] = __builtin_amdgcn_mfma_f32_16x16x32_bf16(a[rf], bfr[cf],
                                                              acc[rf][cf], 0, 0, 0);
  }

  // ---- epilogue: fragment-order stores (+ fused k-stats for mode 0) ----
#pragma unroll
  for (int cf = 0; cf < 4; ++cf) {
    const int col = (wc << 6) + (cf << 4) + u;
    const float bv = bias[col];
    float s = 0.f, sq = 0.f;
#pragma unroll
    for (int rf = 0; rf < 4; ++rf) {
      if (mode == 0) {
        // klin: [win][h][cf_tok][g][u][8j]; token = (rf<<4)+(g<<2)+r, ch=col
        const int hh = col >> 5;
        const int ga = (col >> 3) & 3;
        const int j = col & 7;
        const size_t base =
            ((size_t)((win << 3) | hh) << 11) + (rf << 9) + (ga << 7) + j;
#pragma unroll
        for (int r = 0; r < 4; ++r) {
          u16 hv = f2b(acc[rf][cf][r] + bv);
          dst[base + (((g << 2) + r) << 3)] = hv;
          float rv = b2f(hv);
          s += rv;
          sq = fmaf(rv, rv, sq);
        }
      } else {
        // vt: [win][h][df][ks][g][u][8j]; d-ch = col, token = (rf<<4)+(g<<2)+r
        const int hh = col >> 5;
        const int df = (col >> 4) & 1;
        const int ks_ = rf >> 1;
        const int ga = ((rf & 1) << 1) | (g >> 1);
        const size_t base = ((size_t)((win << 3) | hh) << 11) + (df << 10) +
                            (ks_ << 9) + (ga << 7) + (u << 3) + ((g & 1) << 2);
        u32 w0 = pk2(acc[rf][cf][0] + bv, acc[rf][cf][1] + bv);
        u32 w1 = pk2(acc[rf][cf][2] + bv, acc[rf][cf][3] + bv);
        *(uint2*)(dst + base) = make_uint2(w0, w1);
      }
    }
    if (mode == 0) {
      s += __shfl_xor(s, 16);
      s += __shfl_xor(s, 32);
      sq += __shfl_xor(sq, 16);
      sq += __shfl_xor(sq, 32);
      if (g == 0) {
        kps[(win << 8) + col] = s;
        kpq[(win << 8) + col] = sq;
      }
    }
  }
}

// ---------------------------------------------------------------------------
// Fused attention + projection (unchanged). Block = window (1024), 512 thr =
// 8 waves, wave = head. 2 barriers. Strides P=72, Xl=264.
// ---------------------------------------------------------------------------
union AttnSh {
  u16 P[8][64][72];     // 73728 B
  u16 Xl[2][64][264];   // 67584 B
};

__global__ __launch_bounds__(512) void attn_mega(
    const float* __restrict__ qsrc, const float* __restrict__ qA_,
    const float* __restrict__ qB_, const u16* __restrict__ klin,
    const float* __restrict__ kA_, const float* __restrict__ kB_,
    const u16* __restrict__ vt, const float* __restrict__ rpbm,
    const u16* __restrict__ pwf, const float* __restrict__ pbias,
    float* __restrict__ outp) {
  __shared__ AttnSh sh;
  const int tid = threadIdx.x;
  const int wid = tid >> 6;      // head
  const int l = tid & 63;
  const int u = l & 15;
  const int g = l >> 4;
  const int win = blockIdx.x;
  const int h = wid;
  const int b = win >> 6;
  const int wIdx = win & 63;
  const int wh = wIdx >> 3, ww = wIdx & 7;
  const int var = ((wh == 7) ? 2 : 0) | ((ww == 7) ? 1 : 0);
  const int coff = (h << 5) + (g << 3);

  float qav[8], qbv[8], kav[8], kbv[8];
  {
    const int o = (b << 8) + coff;
    float4 a0 = *(const float4*)(qA_ + o), a1 = *(const float4*)(qA_ + o + 4);
    float4 b0 = *(const float4*)(qB_ + o), b1 = *(const float4*)(qB_ + o + 4);
    float4 c0v = *(const float4*)(kA_ + o), c1 = *(const float4*)(kA_ + o + 4);
    float4 d0v = *(const float4*)(kB_ + o), d1 = *(const float4*)(kB_ + o + 4);
    qav[0]=a0.x;qav[1]=a0.y;qav[2]=a0.z;qav[3]=a0.w;qav[4]=a1.x;qav[5]=a1.y;qav[6]=a1.z;qav[7]=a1.w;
    qbv[0]=b0.x;qbv[1]=b0.y;qbv[2]=b0.z;qbv[3]=b0.w;qbv[4]=b1.x;qbv[5]=b1.y;qbv[6]=b1.z;qbv[7]=b1.w;
    kav[0]=c0v.x;kav[1]=c0v.y;kav[2]=c0v.z;kav[3]=c0v.w;kav[4]=c1.x;kav[5]=c1.y;kav[6]=c1.z;kav[7]=c1.w;
    kbv[0]=d0v.x;kbv[1]=d0v.y;kbv[2]=d0v.z;kbv[3]=d0v.w;kbv[4]=d1.x;kbv[5]=d1.y;kbv[6]=d1.z;kbv[7]=d1.w;
  }

  // q fragments (gathered + normalized + scaled)
  bf16x8 qf[4];
#pragma unroll
  for (int rf = 0; rf < 4; ++rf) {
    const int n = (rf << 4) + u;
    const int nhs = (wh << 3) + (n >> 3);
    const int nws = (ww << 3) + (n & 7);
    const float* qp = qsrc +
        ((((size_t)((b << 6) | ((nhs + 4) & 63)) << 6) | ((nws + 4) & 63)) << 8) + coff;
    float4 v0 = *(const float4*)qp;
    float4 v1 = *(const float4*)(qp + 4);
    float qv[8] = {v0.x, v0.y, v0.z, v0.w, v1.x, v1.y, v1.z, v1.w};
#pragma unroll
    for (int j = 0; j < 8; ++j) qf[rf][j] = (short)f2b(fmaf(qv[j], qav[j], qbv[j]));
  }

  // k fragments — fragment-ordered klin: wave read = 64 lanes x 16B contiguous
  const u16* kp = klin + ((size_t)((win << 3) | h) << 11);
  bf16x8 kf[4];
#pragma unroll
  for (int cf = 0; cf < 4; ++cf) {
    union { uint4 v; u16 s[8]; } raw;
    raw.v = *(const uint4*)(kp + (cf << 9) + (g << 7) + (u << 3));
#pragma unroll
    for (int j = 0; j < 8; ++j)
      kf[cf][j] = (short)f2b(fmaf(b2f(raw.s[j]), kav[j], kbv[j]));
  }

  // S = q k^T
  f32x4 s[4][4];
  const f32x4 z4 = {0.f, 0.f, 0.f, 0.f};
#pragma unroll
  for (int rf = 0; rf < 4; ++rf)
#pragma unroll
    for (int cf = 0; cf < 4; ++cf)
      s[rf][cf] = __builtin_amdgcn_mfma_f32_16x16x32_bf16(qf[rf], kf[cf], z4, 0, 0, 0);

  // + rpb + mask (pre-fused, fragment order)
  const float* rb = rpbm + ((((var << 3) + h) << 6) + l) * 64;
#pragma unroll
  for (int cf = 0; cf < 4; ++cf)
#pragma unroll
    for (int rf = 0; rf < 4; ++rf) {
      float4 bv = *(const float4*)(rb + (cf << 4) + (rf << 2));
      s[rf][cf][0] += bv.x; s[rf][cf][1] += bv.y;
      s[rf][cf][2] += bv.z; s[rf][cf][3] += bv.w;
    }

  // softmax over m (4 col-frags x 16 lanes)
#pragma unroll
  for (int rf = 0; rf < 4; ++rf) {
#pragma unroll
    for (int r = 0; r < 4; ++r) {
      float m0 = fmaxf(fmaxf(s[rf][0][r], s[rf][1][r]),
                       fmaxf(s[rf][2][r], s[rf][3][r]));
      m0 = fmaxf(m0, __shfl_xor(m0, 1));
      m0 = fmaxf(m0, __shfl_xor(m0, 2));
      m0 = fmaxf(m0, __shfl_xor(m0, 4));
      m0 = fmaxf(m0, __shfl_xor(m0, 8));
      float t0 = 0.f;
#pragma unroll
      for (int cf = 0; cf < 4; ++cf) {
        s[rf][cf][r] = __expf(s[rf][cf][r] - m0);
        t0 += s[rf][cf][r];
      }
      t0 += __shfl_xor(t0, 1);
      t0 += __shfl_xor(t0, 2);
      t0 += __shfl_xor(t0, 4);
      t0 += __shfl_xor(t0, 8);
      const float inv = 1.f / t0;
#pragma unroll
      for (int cf = 0; cf < 4; ++cf) s[rf][cf][r] *= inv;
    }
  }

  // P -> LDS (wave-private; own-wave readback needs no barrier)
#pragma unroll
  for (int rf = 0; rf < 4; ++rf)
#pragma unroll
    for (int r = 0; r < 4; ++r) {
      const int n = (rf << 4) + (g << 2) + r;
#pragma unroll
      for (int cf = 0; cf < 4; ++cf)
        sh.P[wid][n][(cf << 4) + u] = f2b(s[rf][cf][r]);
    }

  // pf fragments into regs (lane-transpose), once for both branches
  bf16x8 pf[4][2];
#pragma unroll
  for (int cf = 0; cf < 4; ++cf)
#pragma unroll
    for (int ks = 0; ks < 2; ++ks)
      pf[cf][ks] = *(const bf16x8*)&sh.P[wid][(cf << 4) + u][(ks << 5) + (g << 3)];

  __syncthreads();  // barrier #1: all waves hold pf -> P space reusable as Xl

  // PV per branch (xt reused -> lower register liveness)
  const u16* vbase = vt + ((size_t)((win << 3) | h) << 11);
#pragma unroll
  for (int br = 0; br < 2; ++br) {
    bf16x8 vf[2][2];
#pragma unroll
    for (int df = 0; df < 2; ++df)
#pragma unroll
      for (int ks = 0; ks < 2; ++ks)
        vf[df][ks] = *(const bf16x8*)(vbase + (size_t)br * 16777216 +
                                      (df << 10) + (ks << 9) + (g << 7) + (u << 3));
    f32x4 xt[2][4];
#pragma unroll
    for (int df = 0; df < 2; ++df)
#pragma unroll
      for (int cf = 0; cf < 4; ++cf) xt[df][cf] = z4;
#pragma unroll
    for (int cf = 0; cf < 4; ++cf)
#pragma unroll
      for (int ks = 0; ks < 2; ++ks) {
        xt[0][cf] = __builtin_amdgcn_mfma_f32_16x16x32_bf16(
            vf[0][ks], pf[cf][ks], xt[0][cf], 0, 0, 0);
        xt[1][cf] = __builtin_amdgcn_mfma_f32_16x16x32_bf16(
            vf[1][ks], pf[cf][ks], xt[1][cf], 0, 0, 0);
      }
    // X -> LDS: tok = cf*16+u, ch = h*32 + df*16 + g*4
#pragma unroll
    for (int df = 0; df < 2; ++df)
#pragma unroll
      for (int cf = 0; cf < 4; ++cf) {
        const int tok = (cf << 4) + u;
        const int ch = (h << 5) + (df << 4) + (g << 2);
        *(u32*)&sh.Xl[br][tok][ch] = pk2(xt[df][cf][0], xt[df][cf][1]);
        *(u32*)&sh.Xl[br][tok][ch + 2] = pk2(xt[df][cf][2], xt[df][cf][3]);
      }
  }
  __syncthreads();  // barrier #2: Xl complete

  // cooperative proj per branch; wave owns oc in [32*wid, 32*wid+32)
#pragma unroll
  for (int br = 0; br < 2; ++br) {
    f32x4 acc[4][2];
#pragma unroll
    for (int mf = 0; mf < 4; ++mf)
#pragma unroll
      for (int cfi = 0; cfi < 2; ++cfi) acc[mf][cfi] = z4;
#pragma unroll
    for (int ks = 0; ks < 8; ++ks) {
      bf16x8 a[4];
#pragma unroll
      for (int mf = 0; mf < 4; ++mf)
        a[mf] = *(const bf16x8*)&sh.Xl[br][(mf << 4) + u][(ks << 5) + (g << 3)];
      bf16x8 bw[2];
#pragma unroll
      for (int cfi = 0; cfi < 2; ++cfi) {
        const int cf = (wid << 1) | cfi;
        bw[cfi] = *(const bf16x8*)(pwf +
            ((((((size_t)(cf << 3) | ks) << 2) | g) << 4 | u) << 3));
      }
#pragma unroll
      for (int mf = 0; mf < 4; ++mf)
#pragma unroll
        for (int cfi = 0; cfi < 2; ++cfi)
          acc[mf][cfi] = __builtin_amdgcn_mfma_f32_16x16x32_bf16(
              a[mf], bw[cfi], acc[mf][cfi], 0, 0, 0);
    }

    // epilogue: +bias, reverse-shift scatter
    float* ob = outp + (size_t)br * 16777216;
#pragma unroll
    for (int cfi = 0; cfi < 2; ++cfi) {
      const int oc = (((wid << 1) | cfi) << 4) + u;
      const float bv = pbias[oc];
#pragma unroll
      for (int mf = 0; mf < 4; ++mf) {
#pragma unroll
        for (int r = 0; r < 4; ++r) {
          const int tok = (mf << 4) + (g << 2) + r;
          const int nhs = (wh << 3) + (tok >> 3);
          const int nws = (ww << 3) + (tok & 7);
          ob[((((size_t)((b << 6) | ((nhs + 4) & 63)) << 6) |
               ((nws + 4) & 63)) << 8) + oc] = acc[mf][cfi][r] + bv;
        }
      }
    }
  }
}

// ---------------------------------------------------------------------------
extern "C" void kernel_launch(void* const* d_in, const int* in_sizes, int n_in,
                              void* d_out, int out_size, void* d_ws,
                              size_t ws_size, hipStream_t stream) {
  (void)in_sizes; (void)n_in; (void)out_size; (void)ws_size;
  const float* q   = (const float*)d_in[0];
  const float* k   = (const float*)d_in[1];
  const float* vs  = (const float*)d_in[2];
  const float* vsh = (const float*)d_in[3];
  const float* kW  = (const float*)d_in[4];
  const float* kb  = (const float*)d_in[5];
  const float* vWs = (const float*)d_in[6];
  const float* vbs = (const float*)d_in[7];
  const float* vWh = (const float*)d_in[8];
  const float* vbh = (const float*)d_in[9];
  const float* pW  = (const float*)d_in[10];
  const float* pb  = (const float*)d_in[11];
  const float* rpb = (const float*)d_in[12];
  float* out = (float*)d_out;

  float* f = (float*)d_ws;
  float* qps = f;                       // 262144
  float* qpq = f + 262144;              // 262144
  float* kps = f + 524288;              // 262144
  float* kpq = f + 786432;              // 262144
  float* qA  = f + 1048576;
  float* qB  = f + 1052672;
  float* kA  = f + 1056768;
  float* kB  = f + 1060864;
  float* rpbm = f + 1064960;            // 131072 floats
  u16* wfall = (u16*)(f + 1196032);     // 4 x 65536 u16 = 131072 floats
  u16* klin  = (u16*)(f + 1327104);     // 16.77M u16 = 8388608 floats
  u16* vt    = (u16*)(f + 9715712);     // 33.55M u16 (2 branches)
  u16* pwf   = wfall + 3 * 65536;

  stats_f32<<<1024, 256, 0, stream>>>(q, qps, qpq);
  finalize_stats<<<16, 256, 0, stream>>>(qps, qpq, qA, qB,
                                         0.17677669529663687f);  // 1/sqrt(32)
  rpbm_prep<<<512, 256, 0, stream>>>(rpb, rpbm);
  wf_prep<<<dim3(32, 4), 256, 0, stream>>>(kW, vWs, vWh, pW, wfall);

  gemm_fullk<<<dim3(1024, 3), 256, 0, stream>>>(k, vs, vsh, wfall,
                                                kb, vbs, vbh,
                                                klin, vt, kps, kpq);
  finalize_stats<<<16, 256, 0, stream>>>(kps, kpq, kA, kB, 1.0f);

  attn_mega<<<1024, 512, 0, stream>>>(q, qA, qB, klin, kA, kB, vt, rpbm,
                                      pwf, pb, out);
}

// Round 18
// 182.480 us; speedup vs baseline: 1.3052x; 1.0376x over previous
//
#include <hip/hip_runtime.h>

// ============================================================================
// ShiftedWindowAttention — bf16 MFMA pipeline, v18.
// B=16,H=W=64,C=256,NH=8,HD=32, win 8x8 (N=64), shift 4 -> 1024 windows.
//
// wf_prep -> gemm_all (grid 1024x5: y0-2 = k/v_s/v_sh GEMM, y3 = q-stats,
// y4 = rpbm; prep blocks backfill the latency-bound gemm) -> finalize_both
// -> attn_mega (= v16, known-good).
//
// Round-18: v17 raced — wf was written (y=5) and read (y=0..2) in the SAME
// launch; workgroup dispatch order is undefined -> garbage weights. Fix:
// wf_prep is its own (tiny) prior launch. stats/rpbm fusion kept (their
// consumers are later dispatches). attn reverted to v16 exactly.
// ============================================================================

typedef unsigned short u16;
typedef unsigned int u32;
typedef __attribute__((ext_vector_type(8))) short bf16x8;   // 8 bf16 = 4 VGPR
typedef __attribute__((ext_vector_type(4))) float f32x4;

__device__ __forceinline__ float b2f(u16 u) {
  return __uint_as_float(((u32)u) << 16);
}
// native conversion -> v_cvt_pk_bf16_f32 (RNE)
__device__ __forceinline__ u16 f2b(float f) {
  return __builtin_bit_cast(u16, (__bf16)f);
}
__device__ __forceinline__ u32 pk2(float a, float b) {
  return (u32)f2b(a) | ((u32)f2b(b) << 16);
}
__device__ __forceinline__ bf16x8 pk8(float4 v0, float4 v1) {
  uint4 w;
  w.x = pk2(v0.x, v0.y); w.y = pk2(v0.z, v0.w);
  w.z = pk2(v1.x, v1.y); w.w = pk2(v1.z, v1.w);
  return __builtin_bit_cast(bf16x8, w);
}

// ---------------------------------------------------------------------------
// All weights -> bf16 fragment order wf[w][cf][ks][g][u][8]:
// oc = cf*16+u, ic = ks*32+g*8+j.  w: 0=kW 1=vWs 2=vWh 3=pW.
// MUST run before gemm_all (its consumer).
// ---------------------------------------------------------------------------
__global__ __launch_bounds__(256) void wf_prep(const float* __restrict__ w0,
                                               const float* __restrict__ w1,
                                               const float* __restrict__ w2,
                                               const float* __restrict__ w3,
                                               u16* __restrict__ wf) {
  const int idx = blockIdx.x * 256 + threadIdx.x;  // 8192 per weight
  const int u_ = idx & 15, g_ = (idx >> 4) & 3, ks_ = (idx >> 6) & 7,
            cf_ = idx >> 9;
  const int oc = (cf_ << 4) + u_, ic = (ks_ << 5) + (g_ << 3);
  const float* srcs[4] = {w0, w1, w2, w3};
  const float* p = srcs[blockIdx.y] + (size_t)oc * 256 + ic;
  float4 v0 = *(const float4*)p;
  float4 v1 = *(const float4*)(p + 4);
  *(bf16x8*)(wf + (size_t)blockIdx.y * 65536 + (size_t)idx * 8) = pk8(v0, v1);
}

// ---------------------------------------------------------------------------
// Mega launch: gemm (y=0..2) + q-stats (y=3) + rpbm (y=4). 256 thr.
// ---------------------------------------------------------------------------
__global__ __launch_bounds__(256, 4) void gemm_all(
    const float* __restrict__ ksrc, const float* __restrict__ vs,
    const float* __restrict__ vsh, const u16* __restrict__ wf_r,
    const float* __restrict__ kbias, const float* __restrict__ vbs,
    const float* __restrict__ vbh, u16* __restrict__ klin,
    u16* __restrict__ vt, float* __restrict__ kps, float* __restrict__ kpq,
    const float* __restrict__ qsrc, float* __restrict__ qps,
    float* __restrict__ qpq, const float* __restrict__ rpb,
    float* __restrict__ rpbm) {
  const int t = threadIdx.x;
  const int bx = blockIdx.x;
  const int y = blockIdx.y;

  if (y == 3) {
    // ---- q stats partials: blk = bx (1024), thread = channel ----
    const int b = bx >> 6;
    const int p0 = (bx & 63) << 6;
    const float* p = qsrc + (((size_t)(b << 12) + p0) << 8) + t;
    float s = 0.f, sq = 0.f;
#pragma unroll 8
    for (int i = 0; i < 64; ++i) {
      float v = p[(size_t)i << 8];
      s += v;
      sq = fmaf(v, v, sq);
    }
    qps[(bx << 8) + t] = s;
    qpq[(bx << 8) + t] = sq;
    return;
  }
  if (y == 4) {
    // ---- rpb + mask fused, fragment order (512 blocks worth) ----
    if (bx >= 512) return;
    const int idx = bx * 256 + t;  // 131072
    const int tt = idx & 63;
    const int lane = (idx >> 6) & 63;
    const int h = (idx >> 12) & 7;
    const int var = idx >> 15;
    const int cf = tt >> 4, rf = (tt >> 2) & 3, r = tt & 3;
    const int n = ((lane >> 4) << 2) + r + (rf << 4);
    const int m = (lane & 15) + (cf << 4);
    const int vh = var >> 1, vw = var & 1;
    const int ln = (vh ? (1 + ((n >> 3) >= 4)) : 0) * 3 + (vw ? (1 + ((n & 7) >= 4)) : 0);
    const int lm = (vh ? (1 + ((m >> 3) >= 4)) : 0) * 3 + (vw ? (1 + ((m & 7) >= 4)) : 0);
    rpbm[idx] = rpb[(h << 12) + (n << 6) + m] + ((ln == lm) ? 0.f : -100.f);
    return;
  }

  // ---- y = 0..2: full-K stage-once GEMM, BM=64 (one window per block) ----
  const int mode = y;
  const float* src;
  const float* bias;
  u16* dst;
  if (mode == 0)      { src = ksrc; bias = kbias; dst = klin; }
  else if (mode == 1) { src = vs;   bias = vbs;  dst = vt; }
  else                { src = vsh;  bias = vbh;  dst = vt + 16777216; }
  const u16* wfm = wf_r + (size_t)mode * 65536;

  __shared__ u16 A_s[64][264];
  const int win = bx;

  // stage A panel: wave stages 16 rows; per row the wave reads 1KB contiguous
  {
    const int wv = t >> 6;
    const int lj = t & 63;
#pragma unroll
    for (int it = 0; it < 16; ++it) {
      const int row = (wv << 4) + it;
      const int rg = (bx << 6) + row;
      const int bb = rg >> 12, rr = rg & 4095, wi = rr >> 6, nn = rr & 63;
      const int hs = ((wi >> 3) << 3) + (nn >> 3);
      const int wsq = ((wi & 7) << 3) + (nn & 7);
      const float* ap = src +
          ((((size_t)((bb << 6) | ((hs + 4) & 63)) << 6) | ((wsq + 4) & 63)) << 8) +
          (lj << 2);
      float4 v = *(const float4*)ap;
      *(uint2*)&A_s[row][lj << 2] = make_uint2(pk2(v.x, v.y), pk2(v.z, v.w));
    }
  }
  __syncthreads();  // the only barrier

  const int wc = t >> 6, l = t & 63, u = l & 15, g = l >> 4;

  f32x4 acc[4][4];
#pragma unroll
  for (int i = 0; i < 4; ++i)
#pragma unroll
    for (int j = 0; j < 4; ++j) acc[i][j] = {0.f, 0.f, 0.f, 0.f};

#pragma unroll
  for (int ks = 0; ks < 8; ++ks) {
    bf16x8 bfr[4];
#pragma unroll
    for (int cf = 0; cf < 4; ++cf)
      bfr[cf] = *(const bf16x8*)(wfm +
          ((((size_t)(((wc << 2) | cf) << 3) | ks) << 2 | g) << 4 | u) * 8);
    bf16x8 a[4];
#pragma unroll
    for (int rf = 0; rf < 4; ++rf)
      a[rf] = *(const bf16x8*)&A_s[(rf << 4) + u][(ks << 5) + (g << 3)];
#pragma unroll
    for (int rf = 0; rf < 4; ++rf)
#pragma unroll
      for (int cf = 0; cf < 4; ++cf)
        acc[rf][cf] = __builtin_amdgcn_mfma_f32_16x16x32_bf16(a[rf], bfr[cf],
                                                              acc[rf][cf], 0, 0, 0);
  }

  // epilogue: fragment-order stores (+ fused k-stats for mode 0)
#pragma unroll
  for (int cf = 0; cf < 4; ++cf) {
    const int col = (wc << 6) + (cf << 4) + u;
    const float bv = bias[col];
    float s = 0.f, sq = 0.f;
#pragma unroll
    for (int rf = 0; rf < 4; ++rf) {
      if (mode == 0) {
        // klin: [win][h][cf_tok][g][u][8j]; token = (rf<<4)+(g<<2)+r, ch=col
        const int hh = col >> 5;
        const int ga = (col >> 3) & 3;
        const int j = col & 7;
        const size_t base =
            ((size_t)((win << 3) | hh) << 11) + (rf << 9) + (ga << 7) + j;
#pragma unroll
        for (int r = 0; r < 4; ++r) {
          u16 hv = f2b(acc[rf][cf][r] + bv);
          dst[base + (((g << 2) + r) << 3)] = hv;
          float rv = b2f(hv);
          s += rv;
          sq = fmaf(rv, rv, sq);
        }
      } else {
        // vt: [win][h][df][ks][g][u][8j]; d-ch = col, token = (rf<<4)+(g<<2)+r
        const int hh = col >> 5;
        const int df = (col >> 4) & 1;
        const int ks_ = rf >> 1;
        const int ga = ((rf & 1) << 1) | (g >> 1);
        const size_t base = ((size_t)((win << 3) | hh) << 11) + (df << 10) +
                            (ks_ << 9) + (ga << 7) + (u << 3) + ((g & 1) << 2);
        u32 w0 = pk2(acc[rf][cf][0] + bv, acc[rf][cf][1] + bv);
        u32 w1 = pk2(acc[rf][cf][2] + bv, acc[rf][cf][3] + bv);
        *(uint2*)(dst + base) = make_uint2(w0, w1);
      }
    }
    if (mode == 0) {
      s += __shfl_xor(s, 16);
      s += __shfl_xor(s, 32);
      sq += __shfl_xor(sq, 16);
      sq += __shfl_xor(sq, 32);
      if (g == 0) {
        kps[(win << 8) + col] = s;
        kpq[(win << 8) + col] = sq;
      }
    }
  }
}

// ---------------------------------------------------------------------------
// Merged finalize: 32 blocks x 256. bx<16 -> q (scale 1/sqrt32), else k.
// ---------------------------------------------------------------------------
__global__ void finalize_both(const float* __restrict__ qps,
                              const float* __restrict__ qpq,
                              const float* __restrict__ kps,
                              const float* __restrict__ kpq,
                              float* __restrict__ qA, float* __restrict__ qB,
                              float* __restrict__ kA, float* __restrict__ kB) {
  const int bx = blockIdx.x;
  const bool isq = bx < 16;
  const int i = (isq ? bx : bx - 16) * 256 + threadIdx.x;  // 4096
  const int b = i >> 8, c = i & 255;
  const float* s0 = (isq ? qps : kps) + ((size_t)(b << 6) << 8) + c;
  const float* q0 = (isq ? qpq : kpq) + ((size_t)(b << 6) << 8) + c;
  float s = 0.f, sq = 0.f;
#pragma unroll 8
  for (int j = 0; j < 64; ++j) {
    s += s0[(size_t)j << 8];
    sq += q0[(size_t)j << 8];
  }
  float m = s * (1.f / 4096.f);
  float v = sq * (1.f / 4096.f) - m * m;
  float a = rsqrtf(v + 1e-5f) * (isq ? 0.17677669529663687f : 1.0f);
  (isq ? qA : kA)[i] = a;
  (isq ? qB : kB)[i] = -m * a;
}

// ---------------------------------------------------------------------------
// Fused attention + projection (= v16 exactly). Block = window (1024),
// 512 thr = 8 waves, wave = head. 2 barriers. Strides P=72, Xl=264.
// ---------------------------------------------------------------------------
union AttnSh {
  u16 P[8][64][72];     // 73728 B
  u16 Xl[2][64][264];   // 67584 B
};

__global__ __launch_bounds__(512) void attn_mega(
    const float* __restrict__ qsrc, const float* __restrict__ qA_,
    const float* __restrict__ qB_, const u16* __restrict__ klin,
    const float* __restrict__ kA_, const float* __restrict__ kB_,
    const u16* __restrict__ vt, const float* __restrict__ rpbm,
    const u16* __restrict__ pwf, const float* __restrict__ pbias,
    float* __restrict__ outp) {
  __shared__ AttnSh sh;
  const int tid = threadIdx.x;
  const int wid = tid >> 6;      // head
  const int l = tid & 63;
  const int u = l & 15;
  const int g = l >> 4;
  const int win = blockIdx.x;
  const int h = wid;
  const int b = win >> 6;
  const int wIdx = win & 63;
  const int wh = wIdx >> 3, ww = wIdx & 7;
  const int var = ((wh == 7) ? 2 : 0) | ((ww == 7) ? 1 : 0);
  const int coff = (h << 5) + (g << 3);

  float qav[8], qbv[8], kav[8], kbv[8];
  {
    const int o = (b << 8) + coff;
    float4 a0 = *(const float4*)(qA_ + o), a1 = *(const float4*)(qA_ + o + 4);
    float4 b0 = *(const float4*)(qB_ + o), b1 = *(const float4*)(qB_ + o + 4);
    float4 c0v = *(const float4*)(kA_ + o), c1 = *(const float4*)(kA_ + o + 4);
    float4 d0v = *(const float4*)(kB_ + o), d1 = *(const float4*)(kB_ + o + 4);
    qav[0]=a0.x;qav[1]=a0.y;qav[2]=a0.z;qav[3]=a0.w;qav[4]=a1.x;qav[5]=a1.y;qav[6]=a1.z;qav[7]=a1.w;
    qbv[0]=b0.x;qbv[1]=b0.y;qbv[2]=b0.z;qbv[3]=b0.w;qbv[4]=b1.x;qbv[5]=b1.y;qbv[6]=b1.z;qbv[7]=b1.w;
    kav[0]=c0v.x;kav[1]=c0v.y;kav[2]=c0v.z;kav[3]=c0v.w;kav[4]=c1.x;kav[5]=c1.y;kav[6]=c1.z;kav[7]=c1.w;
    kbv[0]=d0v.x;kbv[1]=d0v.y;kbv[2]=d0v.z;kbv[3]=d0v.w;kbv[4]=d1.x;kbv[5]=d1.y;kbv[6]=d1.z;kbv[7]=d1.w;
  }

  // q fragments (gathered + normalized + scaled)
  bf16x8 qf[4];
#pragma unroll
  for (int rf = 0; rf < 4; ++rf) {
    const int n = (rf << 4) + u;
    const int nhs = (wh << 3) + (n >> 3);
    const int nws = (ww << 3) + (n & 7);
    const float* qp = qsrc +
        ((((size_t)((b << 6) | ((nhs + 4) & 63)) << 6) | ((nws + 4) & 63)) << 8) + coff;
    float4 v0 = *(const float4*)qp;
    float4 v1 = *(const float4*)(qp + 4);
    float qv[8] = {v0.x, v0.y, v0.z, v0.w, v1.x, v1.y, v1.z, v1.w};
#pragma unroll
    for (int j = 0; j < 8; ++j) qf[rf][j] = (short)f2b(fmaf(qv[j], qav[j], qbv[j]));
  }

  // k fragments — fragment-ordered klin: wave read = 64 lanes x 16B contiguous
  const u16* kp = klin + ((size_t)((win << 3) | h) << 11);
  bf16x8 kf[4];
#pragma unroll
  for (int cf = 0; cf < 4; ++cf) {
    union { uint4 v; u16 s[8]; } raw;
    raw.v = *(const uint4*)(kp + (cf << 9) + (g << 7) + (u << 3));
#pragma unroll
    for (int j = 0; j < 8; ++j)
      kf[cf][j] = (short)f2b(fmaf(b2f(raw.s[j]), kav[j], kbv[j]));
  }

  // S = q k^T
  f32x4 s[4][4];
  const f32x4 z4 = {0.f, 0.f, 0.f, 0.f};
#pragma unroll
  for (int rf = 0; rf < 4; ++rf)
#pragma unroll
    for (int cf = 0; cf < 4; ++cf)
      s[rf][cf] = __builtin_amdgcn_mfma_f32_16x16x32_bf16(qf[rf], kf[cf], z4, 0, 0, 0);

  // + rpb + mask (pre-fused, fragment order)
  const float* rb = rpbm + ((((var << 3) + h) << 6) + l) * 64;
#pragma unroll
  for (int cf = 0; cf < 4; ++cf)
#pragma unroll
    for (int rf = 0; rf < 4; ++rf) {
      float4 bv = *(const float4*)(rb + (cf << 4) + (rf << 2));
      s[rf][cf][0] += bv.x; s[rf][cf][1] += bv.y;
      s[rf][cf][2] += bv.z; s[rf][cf][3] += bv.w;
    }

  // softmax over m (4 col-frags x 16 lanes)
#pragma unroll
  for (int rf = 0; rf < 4; ++rf) {
#pragma unroll
    for (int r = 0; r < 4; ++r) {
      float m0 = fmaxf(fmaxf(s[rf][0][r], s[rf][1][r]),
                       fmaxf(s[rf][2][r], s[rf][3][r]));
      m0 = fmaxf(m0, __shfl_xor(m0, 1));
      m0 = fmaxf(m0, __shfl_xor(m0, 2));
      m0 = fmaxf(m0, __shfl_xor(m0, 4));
      m0 = fmaxf(m0, __shfl_xor(m0, 8));
      float t0 = 0.f;
#pragma unroll
      for (int cf = 0; cf < 4; ++cf) {
        s[rf][cf][r] = __expf(s[rf][cf][r] - m0);
        t0 += s[rf][cf][r];
      }
      t0 += __shfl_xor(t0, 1);
      t0 += __shfl_xor(t0, 2);
      t0 += __shfl_xor(t0, 4);
      t0 += __shfl_xor(t0, 8);
      const float inv = 1.f / t0;
#pragma unroll
      for (int cf = 0; cf < 4; ++cf) s[rf][cf][r] *= inv;
    }
  }

  // P -> LDS (wave-private; own-wave readback needs no barrier)
#pragma unroll
  for (int rf = 0; rf < 4; ++rf)
#pragma unroll
    for (int r = 0; r < 4; ++r) {
      const int n = (rf << 4) + (g << 2) + r;
#pragma unroll
      for (int cf = 0; cf < 4; ++cf)
        sh.P[wid][n][(cf << 4) + u] = f2b(s[rf][cf][r]);
    }

  // pf fragments into regs (lane-transpose), once for both branches
  bf16x8 pf[4][2];
#pragma unroll
  for (int cf = 0; cf < 4; ++cf)
#pragma unroll
    for (int ks = 0; ks < 2; ++ks)
      pf[cf][ks] = *(const bf16x8*)&sh.P[wid][(cf << 4) + u][(ks << 5) + (g << 3)];

  __syncthreads();  // barrier #1: all waves hold pf -> P space reusable as Xl

  // PV per branch (xt reused -> lower register liveness)
  const u16* vbase = vt + ((size_t)((win << 3) | h) << 11);
#pragma unroll
  for (int br = 0; br < 2; ++br) {
    bf16x8 vf[2][2];
#pragma unroll
    for (int df = 0; df < 2; ++df)
#pragma unroll
      for (int ks = 0; ks < 2; ++ks)
        vf[df][ks] = *(const bf16x8*)(vbase + (size_t)br * 16777216 +
                                      (df << 10) + (ks << 9) + (g << 7) + (u << 3));
    f32x4 xt[2][4];
#pragma unroll
    for (int df = 0; df < 2; ++df)
#pragma unroll
      for (int cf = 0; cf < 4; ++cf) xt[df][cf] = z4;
#pragma unroll
    for (int cf = 0; cf < 4; ++cf)
#pragma unroll
      for (int ks = 0; ks < 2; ++ks) {
        xt[0][cf] = __builtin_amdgcn_mfma_f32_16x16x32_bf16(
            vf[0][ks], pf[cf][ks], xt[0][cf], 0, 0, 0);
        xt[1][cf] = __builtin_amdgcn_mfma_f32_16x16x32_bf16(
            vf[1][ks], pf[cf][ks], xt[1][cf], 0, 0, 0);
      }
    // X -> LDS: tok = cf*16+u, ch = h*32 + df*16 + g*4
#pragma unroll
    for (int df = 0; df < 2; ++df)
#pragma unroll
      for (int cf = 0; cf < 4; ++cf) {
        const int tok = (cf << 4) + u;
        const int ch = (h << 5) + (df << 4) + (g << 2);
        *(u32*)&sh.Xl[br][tok][ch] = pk2(xt[df][cf][0], xt[df][cf][1]);
        *(u32*)&sh.Xl[br][tok][ch + 2] = pk2(xt[df][cf][2], xt[df][cf][3]);
      }
  }
  __syncthreads();  // barrier #2: Xl complete

  // cooperative proj per branch; wave owns oc in [32*wid, 32*wid+32)
#pragma unroll
  for (int br = 0; br < 2; ++br) {
    f32x4 acc[4][2];
#pragma unroll
    for (int mf = 0; mf < 4; ++mf)
#pragma unroll
      for (int cfi = 0; cfi < 2; ++cfi) acc[mf][cfi] = z4;
#pragma unroll
    for (int ks = 0; ks < 8; ++ks) {
      bf16x8 a[4];
#pragma unroll
      for (int mf = 0; mf < 4; ++mf)
        a[mf] = *(const bf16x8*)&sh.Xl[br][(mf << 4) + u][(ks << 5) + (g << 3)];
      bf16x8 bw[2];
#pragma unroll
      for (int cfi = 0; cfi < 2; ++cfi) {
        const int cf = (wid << 1) | cfi;
        bw[cfi] = *(const bf16x8*)(pwf +
            ((((((size_t)(cf << 3) | ks) << 2) | g) << 4 | u) << 3));
      }
#pragma unroll
      for (int mf = 0; mf < 4; ++mf)
#pragma unroll
        for (int cfi = 0; cfi < 2; ++cfi)
          acc[mf][cfi] = __builtin_amdgcn_mfma_f32_16x16x32_bf16(
              a[mf], bw[cfi], acc[mf][cfi], 0, 0, 0);
    }

    // epilogue: +bias, reverse-shift scatter
    float* ob = outp + (size_t)br * 16777216;
#pragma unroll
    for (int cfi = 0; cfi < 2; ++cfi) {
      const int oc = (((wid << 1) | cfi) << 4) + u;
      const float bv = pbias[oc];
#pragma unroll
      for (int mf = 0; mf < 4; ++mf) {
#pragma unroll
        for (int r = 0; r < 4; ++r) {
          const int tok = (mf << 4) + (g << 2) + r;
          const int nhs = (wh << 3) + (tok >> 3);
          const int nws = (ww << 3) + (tok & 7);
          ob[((((size_t)((b << 6) | ((nhs + 4) & 63)) << 6) |
               ((nws + 4) & 63)) << 8) + oc] = acc[mf][cfi][r] + bv;
        }
      }
    }
  }
}

// ---------------------------------------------------------------------------
extern "C" void kernel_launch(void* const* d_in, const int* in_sizes, int n_in,
                              void* d_out, int out_size, void* d_ws,
                              size_t ws_size, hipStream_t stream) {
  (void)in_sizes; (void)n_in; (void)out_size; (void)ws_size;
  const float* q   = (const float*)d_in[0];
  const float* k   = (const float*)d_in[1];
  const float* vs  = (const float*)d_in[2];
  const float* vsh = (const float*)d_in[3];
  const float* kW  = (const float*)d_in[4];
  const float* kb  = (const float*)d_in[5];
  const float* vWs = (const float*)d_in[6];
  const float* vbs = (const float*)d_in[7];
  const float* vWh = (const float*)d_in[8];
  const float* vbh = (const float*)d_in[9];
  const float* pW  = (const float*)d_in[10];
  const float* pb  = (const float*)d_in[11];
  const float* rpb = (const float*)d_in[12];
  float* out = (float*)d_out;

  float* f = (float*)d_ws;
  float* qps = f;                       // 262144
  float* qpq = f + 262144;              // 262144
  float* kps = f + 524288;              // 262144
  float* kpq = f + 786432;              // 262144
  float* qA  = f + 1048576;
  float* qB  = f + 1052672;
  float* kA  = f + 1056768;
  float* kB  = f + 1060864;
  float* rpbm = f + 1064960;            // 131072 floats
  u16* wfall = (u16*)(f + 1196032);     // 4 x 65536 u16 = 131072 floats
  u16* klin  = (u16*)(f + 1327104);     // 16.77M u16 = 8388608 floats
  u16* vt    = (u16*)(f + 9715712);     // 33.55M u16 (2 branches)
  u16* pwf   = wfall + 3 * 65536;

  wf_prep<<<dim3(32, 4), 256, 0, stream>>>(kW, vWs, vWh, pW, wfall);

  gemm_all<<<dim3(1024, 5), 256, 0, stream>>>(
      k, vs, vsh, wfall, kb, vbs, vbh, klin, vt, kps, kpq,
      q, qps, qpq, rpb, rpbm);

  finalize_both<<<32, 256, 0, stream>>>(qps, qpq, kps, kpq, qA, qB, kA, kB);

  attn_mega<<<1024, 512, 0, stream>>>(q, qA, qB, klin, kA, kB, vt, rpbm,
                                      pwf, pb, out);
}

// Round 19
// 182.047 us; speedup vs baseline: 1.3083x; 1.0024x over previous
//
#include <hip/hip_runtime.h>

// ============================================================================
// ShiftedWindowAttention — bf16 MFMA pipeline, v19.
// B=16,H=W=64,C=256,NH=8,HD=32, win 8x8 (N=64), shift 4 -> 1024 windows.
//
// wf_prep -> gemm_all (y0-2 = k/v_s/v_sh GEMM, y3 = q-stats(float4), y4 =
// rpbm) -> finalize_both -> attn_mega (proj: both branches share bw loads).
//
// Round-19: (1) q-stats plane vectorized (float4/lane = 1KB/wave-instr,
// 256 blocks; partial layout keeps finalize contract). (2) attn proj
// interleaves branches in one ks loop (bw loaded once, 2x MFMA per load);
// launch_bounds(512,4) raises the VGPR ceiling to 128 (2 blk/CU is the LDS
// limit anyway) so the wider accumulator set doesn't spill.
// ============================================================================

typedef unsigned short u16;
typedef unsigned int u32;
typedef __attribute__((ext_vector_type(8))) short bf16x8;   // 8 bf16 = 4 VGPR
typedef __attribute__((ext_vector_type(4))) float f32x4;

__device__ __forceinline__ float b2f(u16 u) {
  return __uint_as_float(((u32)u) << 16);
}
// native conversion -> v_cvt_pk_bf16_f32 (RNE)
__device__ __forceinline__ u16 f2b(float f) {
  return __builtin_bit_cast(u16, (__bf16)f);
}
__device__ __forceinline__ u32 pk2(float a, float b) {
  return (u32)f2b(a) | ((u32)f2b(b) << 16);
}
__device__ __forceinline__ bf16x8 pk8(float4 v0, float4 v1) {
  uint4 w;
  w.x = pk2(v0.x, v0.y); w.y = pk2(v0.z, v0.w);
  w.z = pk2(v1.x, v1.y); w.w = pk2(v1.z, v1.w);
  return __builtin_bit_cast(bf16x8, w);
}

// ---------------------------------------------------------------------------
// All weights -> bf16 fragment order wf[w][cf][ks][g][u][8]:
// oc = cf*16+u, ic = ks*32+g*8+j.  w: 0=kW 1=vWs 2=vWh 3=pW.
// MUST run before gemm_all (its consumer).
// ---------------------------------------------------------------------------
__global__ __launch_bounds__(256) void wf_prep(const float* __restrict__ w0,
                                               const float* __restrict__ w1,
                                               const float* __restrict__ w2,
                                               const float* __restrict__ w3,
                                               u16* __restrict__ wf) {
  const int idx = blockIdx.x * 256 + threadIdx.x;  // 8192 per weight
  const int u_ = idx & 15, g_ = (idx >> 4) & 3, ks_ = (idx >> 6) & 7,
            cf_ = idx >> 9;
  const int oc = (cf_ << 4) + u_, ic = (ks_ << 5) + (g_ << 3);
  const float* srcs[4] = {w0, w1, w2, w3};
  const float* p = srcs[blockIdx.y] + (size_t)oc * 256 + ic;
  float4 v0 = *(const float4*)p;
  float4 v1 = *(const float4*)(p + 4);
  *(bf16x8*)(wf + (size_t)blockIdx.y * 65536 + (size_t)idx * 8) = pk8(v0, v1);
}

// ---------------------------------------------------------------------------
// Mega launch: gemm (y=0..2) + q-stats (y=3, float4) + rpbm (y=4). 256 thr.
// ---------------------------------------------------------------------------
__global__ __launch_bounds__(256, 4) void gemm_all(
    const float* __restrict__ ksrc, const float* __restrict__ vs,
    const float* __restrict__ vsh, const u16* __restrict__ wf_r,
    const float* __restrict__ kbias, const float* __restrict__ vbs,
    const float* __restrict__ vbh, u16* __restrict__ klin,
    u16* __restrict__ vt, float* __restrict__ kps, float* __restrict__ kpq,
    const float* __restrict__ qsrc, float* __restrict__ qps,
    float* __restrict__ qpq, const float* __restrict__ rpb,
    float* __restrict__ rpbm) {
  const int t = threadIdx.x;
  const int bx = blockIdx.x;
  const int y = blockIdx.y;

  if (y == 3) {
    // ---- q stats partials, float4: 256 blocks; block = (b, chunk of 256
    //      positions). Thread (pr = t>>6, c4 = (t&63)*4): 64 positions
    //      (p0+pr+4i), 4 channels. Partial row = bx*4+pr (64 rows/batch,
    //      matching finalize). Wave load = 1KB contiguous.
    if (bx >= 256) return;
    const int b = bx >> 4;
    const int p0 = (bx & 15) << 8;
    const int pr = t >> 6;
    const int c4 = (t & 63) << 2;
    const float* p = qsrc + (((size_t)(b << 12) + p0 + pr) << 8) + c4;
    float s[4] = {0.f, 0.f, 0.f, 0.f}, sq[4] = {0.f, 0.f, 0.f, 0.f};
#pragma unroll 8
    for (int i = 0; i < 64; ++i) {
      float4 v = *(const float4*)(p + ((size_t)i << 10));
      s[0] += v.x; sq[0] = fmaf(v.x, v.x, sq[0]);
      s[1] += v.y; sq[1] = fmaf(v.y, v.y, sq[1]);
      s[2] += v.z; sq[2] = fmaf(v.z, v.z, sq[2]);
      s[3] += v.w; sq[3] = fmaf(v.w, v.w, sq[3]);
    }
    const int row = (bx << 2) + pr;
    float4* so = (float4*)(qps + (row << 8) + c4);
    float4* qo = (float4*)(qpq + (row << 8) + c4);
    *so = make_float4(s[0], s[1], s[2], s[3]);
    *qo = make_float4(sq[0], sq[1], sq[2], sq[3]);
    return;
  }
  if (y == 4) {
    // ---- rpb + mask fused, fragment order (512 blocks worth) ----
    if (bx >= 512) return;
    const int idx = bx * 256 + t;  // 131072
    const int tt = idx & 63;
    const int lane = (idx >> 6) & 63;
    const int h = (idx >> 12) & 7;
    const int var = idx >> 15;
    const int cf = tt >> 4, rf = (tt >> 2) & 3, r = tt & 3;
    const int n = ((lane >> 4) << 2) + r + (rf << 4);
    const int m = (lane & 15) + (cf << 4);
    const int vh = var >> 1, vw = var & 1;
    const int ln = (vh ? (1 + ((n >> 3) >= 4)) : 0) * 3 + (vw ? (1 + ((n & 7) >= 4)) : 0);
    const int lm = (vh ? (1 + ((m >> 3) >= 4)) : 0) * 3 + (vw ? (1 + ((m & 7) >= 4)) : 0);
    rpbm[idx] = rpb[(h << 12) + (n << 6) + m] + ((ln == lm) ? 0.f : -100.f);
    return;
  }

  // ---- y = 0..2: full-K stage-once GEMM, BM=64 (one window per block) ----
  const int mode = y;
  const float* src;
  const float* bias;
  u16* dst;
  if (mode == 0)      { src = ksrc; bias = kbias; dst = klin; }
  else if (mode == 1) { src = vs;   bias = vbs;  dst = vt; }
  else                { src = vsh;  bias = vbh;  dst = vt + 16777216; }
  const u16* wfm = wf_r + (size_t)mode * 65536;

  __shared__ u16 A_s[64][264];
  const int win = bx;

  // stage A panel: wave stages 16 rows; per row the wave reads 1KB contiguous
  {
    const int wv = t >> 6;
    const int lj = t & 63;
#pragma unroll
    for (int it = 0; it < 16; ++it) {
      const int row = (wv << 4) + it;
      const int rg = (bx << 6) + row;
      const int bb = rg >> 12, rr = rg & 4095, wi = rr >> 6, nn = rr & 63;
      const int hs = ((wi >> 3) << 3) + (nn >> 3);
      const int wsq = ((wi & 7) << 3) + (nn & 7);
      const float* ap = src +
          ((((size_t)((bb << 6) | ((hs + 4) & 63)) << 6) | ((wsq + 4) & 63)) << 8) +
          (lj << 2);
      float4 v = *(const float4*)ap;
      *(uint2*)&A_s[row][lj << 2] = make_uint2(pk2(v.x, v.y), pk2(v.z, v.w));
    }
  }
  __syncthreads();  // the only barrier

  const int wc = t >> 6, l = t & 63, u = l & 15, g = l >> 4;

  f32x4 acc[4][4];
#pragma unroll
  for (int i = 0; i < 4; ++i)
#pragma unroll
    for (int j = 0; j < 4; ++j) acc[i][j] = {0.f, 0.f, 0.f, 0.f};

#pragma unroll
  for (int ks = 0; ks < 8; ++ks) {
    bf16x8 bfr[4];
#pragma unroll
    for (int cf = 0; cf < 4; ++cf)
      bfr[cf] = *(const bf16x8*)(wfm +
          ((((size_t)(((wc << 2) | cf) << 3) | ks) << 2 | g) << 4 | u) * 8);
    bf16x8 a[4];
#pragma unroll
    for (int rf = 0; rf < 4; ++rf)
      a[rf] = *(const bf16x8*)&A_s[(rf << 4) + u][(ks << 5) + (g << 3)];
#pragma unroll
    for (int rf = 0; rf < 4; ++rf)
#pragma unroll
      for (int cf = 0; cf < 4; ++cf)
        acc[rf][cf] = __builtin_amdgcn_mfma_f32_16x16x32_bf16(a[rf], bfr[cf],
                                                              acc[rf][cf], 0, 0, 0);
  }

  // epilogue: fragment-order stores (+ fused k-stats for mode 0)
#pragma unroll
  for (int cf = 0; cf < 4; ++cf) {
    const int col = (wc << 6) + (cf << 4) + u;
    const float bv = bias[col];
    float s = 0.f, sq = 0.f;
#pragma unroll
    for (int rf = 0; rf < 4; ++rf) {
      if (mode == 0) {
        // klin: [win][h][cf_tok][g][u][8j]; token = (rf<<4)+(g<<2)+r, ch=col
        const int hh = col >> 5;
        const int ga = (col >> 3) & 3;
        const int j = col & 7;
        const size_t base =
            ((size_t)((win << 3) | hh) << 11) + (rf << 9) + (ga << 7) + j;
#pragma unroll
        for (int r = 0; r < 4; ++r) {
          u16 hv = f2b(acc[rf][cf][r] + bv);
          dst[base + (((g << 2) + r) << 3)] = hv;
          float rv = b2f(hv);
          s += rv;
          sq = fmaf(rv, rv, sq);
        }
      } else {
        // vt: [win][h][df][ks][g][u][8j]; d-ch = col, token = (rf<<4)+(g<<2)+r
        const int hh = col >> 5;
        const int df = (col >> 4) & 1;
        const int ks_ = rf >> 1;
        const int ga = ((rf & 1) << 1) | (g >> 1);
        const size_t base = ((size_t)((win << 3) | hh) << 11) + (df << 10) +
                            (ks_ << 9) + (ga << 7) + (u << 3) + ((g & 1) << 2);
        u32 w0 = pk2(acc[rf][cf][0] + bv, acc[rf][cf][1] + bv);
        u32 w1 = pk2(acc[rf][cf][2] + bv, acc[rf][cf][3] + bv);
        *(uint2*)(dst + base) = make_uint2(w0, w1);
      }
    }
    if (mode == 0) {
      s += __shfl_xor(s, 16);
      s += __shfl_xor(s, 32);
      sq += __shfl_xor(sq, 16);
      sq += __shfl_xor(sq, 32);
      if (g == 0) {
        kps[(win << 8) + col] = s;
        kpq[(win << 8) + col] = sq;
      }
    }
  }
}

// ---------------------------------------------------------------------------
// Merged finalize: 32 blocks x 256. bx<16 -> q (scale 1/sqrt32), else k.
// ---------------------------------------------------------------------------
__global__ void finalize_both(const float* __restrict__ qps,
                              const float* __restrict__ qpq,
                              const float* __restrict__ kps,
                              const float* __restrict__ kpq,
                              float* __restrict__ qA, float* __restrict__ qB,
                              float* __restrict__ kA, float* __restrict__ kB) {
  const int bx = blockIdx.x;
  const bool isq = bx < 16;
  const int i = (isq ? bx : bx - 16) * 256 + threadIdx.x;  // 4096
  const int b = i >> 8, c = i & 255;
  const float* s0 = (isq ? qps : kps) + ((size_t)(b << 6) << 8) + c;
  const float* q0 = (isq ? qpq : kpq) + ((size_t)(b << 6) << 8) + c;
  float s = 0.f, sq = 0.f;
#pragma unroll 8
  for (int j = 0; j < 64; ++j) {
    s += s0[(size_t)j << 8];
    sq += q0[(size_t)j << 8];
  }
  float m = s * (1.f / 4096.f);
  float v = sq * (1.f / 4096.f) - m * m;
  float a = rsqrtf(v + 1e-5f) * (isq ? 0.17677669529663687f : 1.0f);
  (isq ? qA : kA)[i] = a;
  (isq ? qB : kB)[i] = -m * a;
}

// ---------------------------------------------------------------------------
// Fused attention + projection. Block = window (1024), 512 thr = 8 waves,
// wave = head. 2 barriers. Strides P=72, Xl=264. Proj: both branches in one
// ks loop sharing bw loads; launch_bounds(512,4) = VGPR cap 128 (LDS already
// limits to 2 blk/CU, so the cap is free headroom, not a squeeze).
// ---------------------------------------------------------------------------
union AttnSh {
  u16 P[8][64][72];     // 73728 B
  u16 Xl[2][64][264];   // 67584 B
};

__global__ __launch_bounds__(512, 4) void attn_mega(
    const float* __restrict__ qsrc, const float* __restrict__ qA_,
    const float* __restrict__ qB_, const u16* __restrict__ klin,
    const float* __restrict__ kA_, const float* __restrict__ kB_,
    const u16* __restrict__ vt, const float* __restrict__ rpbm,
    const u16* __restrict__ pwf, const float* __restrict__ pbias,
    float* __restrict__ outp) {
  __shared__ AttnSh sh;
  const int tid = threadIdx.x;
  const int wid = tid >> 6;      // head
  const int l = tid & 63;
  const int u = l & 15;
  const int g = l >> 4;
  const int win = blockIdx.x;
  const int h = wid;
  const int b = win >> 6;
  const int wIdx = win & 63;
  const int wh = wIdx >> 3, ww = wIdx & 7;
  const int var = ((wh == 7) ? 2 : 0) | ((ww == 7) ? 1 : 0);
  const int coff = (h << 5) + (g << 3);

  float qav[8], qbv[8], kav[8], kbv[8];
  {
    const int o = (b << 8) + coff;
    float4 a0 = *(const float4*)(qA_ + o), a1 = *(const float4*)(qA_ + o + 4);
    float4 b0 = *(const float4*)(qB_ + o), b1 = *(const float4*)(qB_ + o + 4);
    float4 c0v = *(const float4*)(kA_ + o), c1 = *(const float4*)(kA_ + o + 4);
    float4 d0v = *(const float4*)(kB_ + o), d1 = *(const float4*)(kB_ + o + 4);
    qav[0]=a0.x;qav[1]=a0.y;qav[2]=a0.z;qav[3]=a0.w;qav[4]=a1.x;qav[5]=a1.y;qav[6]=a1.z;qav[7]=a1.w;
    qbv[0]=b0.x;qbv[1]=b0.y;qbv[2]=b0.z;qbv[3]=b0.w;qbv[4]=b1.x;qbv[5]=b1.y;qbv[6]=b1.z;qbv[7]=b1.w;
    kav[0]=c0v.x;kav[1]=c0v.y;kav[2]=c0v.z;kav[3]=c0v.w;kav[4]=c1.x;kav[5]=c1.y;kav[6]=c1.z;kav[7]=c1.w;
    kbv[0]=d0v.x;kbv[1]=d0v.y;kbv[2]=d0v.z;kbv[3]=d0v.w;kbv[4]=d1.x;kbv[5]=d1.y;kbv[6]=d1.z;kbv[7]=d1.w;
  }

  // q fragments (gathered + normalized + scaled)
  bf16x8 qf[4];
#pragma unroll
  for (int rf = 0; rf < 4; ++rf) {
    const int n = (rf << 4) + u;
    const int nhs = (wh << 3) + (n >> 3);
    const int nws = (ww << 3) + (n & 7);
    const float* qp = qsrc +
        ((((size_t)((b << 6) | ((nhs + 4) & 63)) << 6) | ((nws + 4) & 63)) << 8) + coff;
    float4 v0 = *(const float4*)qp;
    float4 v1 = *(const float4*)(qp + 4);
    float qv[8] = {v0.x, v0.y, v0.z, v0.w, v1.x, v1.y, v1.z, v1.w};
#pragma unroll
    for (int j = 0; j < 8; ++j) qf[rf][j] = (short)f2b(fmaf(qv[j], qav[j], qbv[j]));
  }

  // k fragments — fragment-ordered klin: wave read = 64 lanes x 16B contiguous
  const u16* kp = klin + ((size_t)((win << 3) | h) << 11);
  bf16x8 kf[4];
#pragma unroll
  for (int cf = 0; cf < 4; ++cf) {
    union { uint4 v; u16 s[8]; } raw;
    raw.v = *(const uint4*)(kp + (cf << 9) + (g << 7) + (u << 3));
#pragma unroll
    for (int j = 0; j < 8; ++j)
      kf[cf][j] = (short)f2b(fmaf(b2f(raw.s[j]), kav[j], kbv[j]));
  }

  // S = q k^T
  f32x4 s[4][4];
  const f32x4 z4 = {0.f, 0.f, 0.f, 0.f};
#pragma unroll
  for (int rf = 0; rf < 4; ++rf)
#pragma unroll
    for (int cf = 0; cf < 4; ++cf)
      s[rf][cf] = __builtin_amdgcn_mfma_f32_16x16x32_bf16(qf[rf], kf[cf], z4, 0, 0, 0);

  // + rpb + mask (pre-fused, fragment order)
  const float* rb = rpbm + ((((var << 3) + h) << 6) + l) * 64;
#pragma unroll
  for (int cf = 0; cf < 4; ++cf)
#pragma unroll
    for (int rf = 0; rf < 4; ++rf) {
      float4 bv = *(const float4*)(rb + (cf << 4) + (rf << 2));
      s[rf][cf][0] += bv.x; s[rf][cf][1] += bv.y;
      s[rf][cf][2] += bv.z; s[rf][cf][3] += bv.w;
    }

  // softmax over m (4 col-frags x 16 lanes)
#pragma unroll
  for (int rf = 0; rf < 4; ++rf) {
#pragma unroll
    for (int r = 0; r < 4; ++r) {
      float m0 = fmaxf(fmaxf(s[rf][0][r], s[rf][1][r]),
                       fmaxf(s[rf][2][r], s[rf][3][r]));
      m0 = fmaxf(m0, __shfl_xor(m0, 1));
      m0 = fmaxf(m0, __shfl_xor(m0, 2));
      m0 = fmaxf(m0, __shfl_xor(m0, 4));
      m0 = fmaxf(m0, __shfl_xor(m0, 8));
      float t0 = 0.f;
#pragma unroll
      for (int cf = 0; cf < 4; ++cf) {
        s[rf][cf][r] = __expf(s[rf][cf][r] - m0);
        t0 += s[rf][cf][r];
      }
      t0 += __shfl_xor(t0, 1);
      t0 += __shfl_xor(t0, 2);
      t0 += __shfl_xor(t0, 4);
      t0 += __shfl_xor(t0, 8);
      const float inv = 1.f / t0;
#pragma unroll
      for (int cf = 0; cf < 4; ++cf) s[rf][cf][r] *= inv;
    }
  }

  // P -> LDS (wave-private; own-wave readback needs no barrier)
#pragma unroll
  for (int rf = 0; rf < 4; ++rf)
#pragma unroll
    for (int r = 0; r < 4; ++r) {
      const int n = (rf << 4) + (g << 2) + r;
#pragma unroll
      for (int cf = 0; cf < 4; ++cf)
        sh.P[wid][n][(cf << 4) + u] = f2b(s[rf][cf][r]);
    }

  // pf fragments into regs (lane-transpose), once for both branches
  bf16x8 pf[4][2];
#pragma unroll
  for (int cf = 0; cf < 4; ++cf)
#pragma unroll
    for (int ks = 0; ks < 2; ++ks)
      pf[cf][ks] = *(const bf16x8*)&sh.P[wid][(cf << 4) + u][(ks << 5) + (g << 3)];

  __syncthreads();  // barrier #1: all waves hold pf -> P space reusable as Xl

  // PV per branch (xt reused -> lower register liveness)
  const u16* vbase = vt + ((size_t)((win << 3) | h) << 11);
#pragma unroll
  for (int br = 0; br < 2; ++br) {
    bf16x8 vf[2][2];
#pragma unroll
    for (int df = 0; df < 2; ++df)
#pragma unroll
      for (int ks = 0; ks < 2; ++ks)
        vf[df][ks] = *(const bf16x8*)(vbase + (size_t)br * 16777216 +
                                      (df << 10) + (ks << 9) + (g << 7) + (u << 3));
    f32x4 xt[2][4];
#pragma unroll
    for (int df = 0; df < 2; ++df)
#pragma unroll
      for (int cf = 0; cf < 4; ++cf) xt[df][cf] = z4;
#pragma unroll
    for (int cf = 0; cf < 4; ++cf)
#pragma unroll
      for (int ks = 0; ks < 2; ++ks) {
        xt[0][cf] = __builtin_amdgcn_mfma_f32_16x16x32_bf16(
            vf[0][ks], pf[cf][ks], xt[0][cf], 0, 0, 0);
        xt[1][cf] = __builtin_amdgcn_mfma_f32_16x16x32_bf16(
            vf[1][ks], pf[cf][ks], xt[1][cf], 0, 0, 0);
      }
    // X -> LDS: tok = cf*16+u, ch = h*32 + df*16 + g*4
#pragma unroll
    for (int df = 0; df < 2; ++df)
#pragma unroll
      for (int cf = 0; cf < 4; ++cf) {
        const int tok = (cf << 4) + u;
        const int ch = (h << 5) + (df << 4) + (g << 2);
        *(u32*)&sh.Xl[br][tok][ch] = pk2(xt[df][cf][0], xt[df][cf][1]);
        *(u32*)&sh.Xl[br][tok][ch + 2] = pk2(xt[df][cf][2], xt[df][cf][3]);
      }
  }
  __syncthreads();  // barrier #2: Xl complete

  // cooperative proj, BOTH branches in one ks loop (bw loaded once);
  // wave owns oc in [32*wid, 32*wid+32)
  f32x4 acc[2][4][2];
#pragma unroll
  for (int br = 0; br < 2; ++br)
#pragma unroll
    for (int mf = 0; mf < 4; ++mf)
#pragma unroll
      for (int cfi = 0; cfi < 2; ++cfi) acc[br][mf][cfi] = z4;
#pragma unroll
  for (int ks = 0; ks < 8; ++ks) {
    bf16x8 a0[4], a1[4];
#pragma unroll
    for (int mf = 0; mf < 4; ++mf) {
      a0[mf] = *(const bf16x8*)&sh.Xl[0][(mf << 4) + u][(ks << 5) + (g << 3)];
      a1[mf] = *(const bf16x8*)&sh.Xl[1][(mf << 4) + u][(ks << 5) + (g << 3)];
    }
    bf16x8 bw[2];
#pragma unroll
    for (int cfi = 0; cfi < 2; ++cfi) {
      const int cf = (wid << 1) | cfi;
      bw[cfi] = *(const bf16x8*)(pwf +
          ((((((size_t)(cf << 3) | ks) << 2) | g) << 4 | u) << 3));
    }
#pragma unroll
    for (int mf = 0; mf < 4; ++mf)
#pragma unroll
      for (int cfi = 0; cfi < 2; ++cfi) {
        acc[0][mf][cfi] = __builtin_amdgcn_mfma_f32_16x16x32_bf16(
            a0[mf], bw[cfi], acc[0][mf][cfi], 0, 0, 0);
        acc[1][mf][cfi] = __builtin_amdgcn_mfma_f32_16x16x32_bf16(
            a1[mf], bw[cfi], acc[1][mf][cfi], 0, 0, 0);
      }
  }

  // epilogue: +bias, reverse-shift scatter, both branches
#pragma unroll
  for (int br = 0; br < 2; ++br) {
    float* ob = outp + (size_t)br * 16777216;
#pragma unroll
    for (int cfi = 0; cfi < 2; ++cfi) {
      const int oc = (((wid << 1) | cfi) << 4) + u;
      const float bv = pbias[oc];
#pragma unroll
      for (int mf = 0; mf < 4; ++mf) {
#pragma unroll
        for (int r = 0; r < 4; ++r) {
          const int tok = (mf << 4) + (g << 2) + r;
          const int nhs = (wh << 3) + (tok >> 3);
          const int nws = (ww << 3) + (tok & 7);
          ob[((((size_t)((b << 6) | ((nhs + 4) & 63)) << 6) |
               ((nws + 4) & 63)) << 8) + oc] = acc[br][mf][cfi][r] + bv;
        }
      }
    }
  }
}

// ---------------------------------------------------------------------------
extern "C" void kernel_launch(void* const* d_in, const int* in_sizes, int n_in,
                              void* d_out, int out_size, void* d_ws,
                              size_t ws_size, hipStream_t stream) {
  (void)in_sizes; (void)n_in; (void)out_size; (void)ws_size;
  const float* q   = (const float*)d_in[0];
  const float* k   = (const float*)d_in[1];
  const float* vs  = (const float*)d_in[2];
  const float* vsh = (const float*)d_in[3];
  const float* kW  = (const float*)d_in[4];
  const float* kb  = (const float*)d_in[5];
  const float* vWs = (const float*)d_in[6];
  const float* vbs = (const float*)d_in[7];
  const float* vWh = (const float*)d_in[8];
  const float* vbh = (const float*)d_in[9];
  const float* pW  = (const float*)d_in[10];
  const float* pb  = (const float*)d_in[11];
  const float* rpb = (const float*)d_in[12];
  float* out = (float*)d_out;

  float* f = (float*)d_ws;
  float* qps = f;                       // 262144
  float* qpq = f + 262144;              // 262144
  float* kps = f + 524288;              // 262144
  float* kpq = f + 786432;              // 262144
  float* qA  = f + 1048576;
  float* qB  = f + 1052672;
  float* kA  = f + 1056768;
  float* kB  = f + 1060864;
  float* rpbm = f + 1064960;            // 131072 floats
  u16* wfall = (u16*)(f + 1196032);     // 4 x 65536 u16 = 131072 floats
  u16* klin  = (u16*)(f + 1327104);     // 16.77M u16 = 8388608 floats
  u16* vt    = (u16*)(f + 9715712);     // 33.55M u16 (2 branches)
  u16* pwf   = wfall + 3 * 65536;

  wf_prep<<<dim3(32, 4), 256, 0, stream>>>(kW, vWs, vWh, pW, wfall);

  gemm_all<<<dim3(1024, 5), 256, 0, stream>>>(
      k, vs, vsh, wfall, kb, vbs, vbh, klin, vt, kps, kpq,
      q, qps, qpq, rpb, rpbm);

  finalize_both<<<32, 256, 0, stream>>>(qps, qpq, kps, kpq, qA, qB, kA, kB);

  attn_mega<<<1024, 512, 0, stream>>>(q, qA, qB, klin, kA, kB, vt, rpbm,
                                      pwf, pb, out);
}